// Round 16
// baseline (728.777 us; speedup 1.0000x reference)
//
#include <hip/hip_runtime.h>
#include <cmath>

typedef __attribute__((ext_vector_type(8))) _Float16 f16x8;
typedef __attribute__((ext_vector_type(8))) unsigned short u16x8;
typedef __attribute__((ext_vector_type(4))) float f32x4;

#define DEV static __device__ __forceinline__

constexpr int Dm   = 1024;
constexpr int HIDm = 2048;
constexpr int NT   = 1024;
constexpr int NV   = 32000;
constexpr float EPSf  = 1e-8f;
constexpr float LOSC  = 4096.0f;
constexpr float ILOSC = 1.0f / 4096.0f;

DEV unsigned short h2u(_Float16 h){ union{_Float16 h; unsigned short u;} v; v.h=h; return v.u; }

DEV f32x4 MF(f16x8 a, f16x8 b, f32x4 c){ return __builtin_amdgcn_mfma_f32_16x16x32_f16(a,b,c,0,0,0); }

typedef __attribute__((address_space(1))) void GV;
typedef __attribute__((address_space(3))) void LV;
DEV void gll16(const void* g, void* l){
  __builtin_amdgcn_global_load_lds((GV*)(__UINTPTR_TYPE__)g, (LV*)l, 16, 0, 0);
}

// BK=32 LDS swizzle (verified conflict-free R8): unit ^= (row>>1)&3
DEV int swk(int lane){ return (((lane&3) ^ ((lane>>3)&3))*8); }
DEV int rdc(int fr, int fg){ return ((fg ^ ((fr>>1)&3))*8); }

template<int SPLIT>
DEV void st_sp(unsigned short* __restrict__ hi, unsigned short* __restrict__ lo, size_t o, float v){
  _Float16 hh = (_Float16)v;
  hi[o] = h2u(hh);
  if constexpr (SPLIT==3) lo[o] = h2u((_Float16)((v - (float)hh)*LOSC));
}

// merged: emb f32->f16 pre-convert (bid<gbase) + token gather + first rms (bid>=gbase)
template<int SPLIT>
__global__ __launch_bounds__(256) void k_init(
    const int* __restrict__ idx, const float* __restrict__ emb,
    float* __restrict__ x, unsigned short* __restrict__ emb16, int gbase,
    const float* __restrict__ anw, unsigned short* __restrict__ hhi,
    unsigned short* __restrict__ hlo)
{
  const int b = blockIdx.x;
  if (b < gbase){
    const size_t i = ((size_t)b*256 + threadIdx.x)*8;
    const float4 v0 = *(const float4*)&emb[i];
    const float4 v1 = *(const float4*)&emb[i+4];
    u16x8 h;
    h[0]=h2u((_Float16)v0.x); h[1]=h2u((_Float16)v0.y);
    h[2]=h2u((_Float16)v0.z); h[3]=h2u((_Float16)v0.w);
    h[4]=h2u((_Float16)v1.x); h[5]=h2u((_Float16)v1.y);
    h[6]=h2u((_Float16)v1.z); h[7]=h2u((_Float16)v1.w);
    *(u16x8*)&emb16[i] = h;
    return;
  }
  const int t = b - gbase, tid = threadIdx.x, wv = tid>>6, lane = tid&63;
  const int c = tid*4;
  const float4 v = *(const float4*)&emb[(size_t)idx[t]*Dm + c];
  *(float4*)&x[(size_t)t*Dm + c] = v;
  float ss = v.x*v.x + v.y*v.y + v.z*v.z + v.w*v.w;
  #pragma unroll
  for (int d=1; d<64; d<<=1) ss += __shfl_xor(ss, d);
  __shared__ float red[4];
  if (lane==0) red[wv] = ss;
  __syncthreads();
  const float rstd = rsqrtf((red[0]+red[1]+red[2]+red[3])*(1.0f/Dm) + EPSf);
  const float4 w4 = *(const float4*)&anw[c];
  const float sv[4] = {v.x,v.y,v.z,v.w};
  const float wv4[4] = {w4.x,w4.y,w4.z,w4.w};
  #pragma unroll
  for (int j=0;j<4;++j)
    st_sp<SPLIT>(hhi, hlo, (size_t)t*Dm + c + j, sv[j]*rstd*wv4[j]);
}

// fused: x += sum(part z=0..7) + ob ; write x ; rms(fnw)->h planes ; router top2 -> cmb
template<int SPLIT>
__global__ __launch_bounds__(256) void k_fuse_o(
    const float* __restrict__ part, const float* __restrict__ ob,
    const float* __restrict__ fnw, const float* __restrict__ rw,
    float* __restrict__ x, unsigned short* __restrict__ hhi,
    unsigned short* __restrict__ hlo, float* __restrict__ cmb)
{
  const int t = blockIdx.x, tid = threadIdx.x, wv = tid>>6, lane = tid&63;
  const int c = tid*4;
  float4 s = *(float4*)&x[(size_t)t*Dm + c];
  #pragma unroll
  for (int z=0; z<8; ++z){
    const float4 p = *(const float4*)&part[((size_t)z*NT + t)*Dm + c];
    s.x+=p.x; s.y+=p.y; s.z+=p.z; s.w+=p.w;
  }
  const float4 b4 = *(const float4*)&ob[c];
  s.x+=b4.x; s.y+=b4.y; s.z+=b4.z; s.w+=b4.w;
  *(float4*)&x[(size_t)t*Dm + c] = s;

  float ss = s.x*s.x + s.y*s.y + s.z*s.z + s.w*s.w;
  #pragma unroll
  for (int d=1; d<64; d<<=1) ss += __shfl_xor(ss, d);
  __shared__ float red[4];
  if (lane==0) red[wv] = ss;
  __syncthreads();
  const float rstd = rsqrtf((red[0]+red[1]+red[2]+red[3])*(1.0f/Dm) + EPSf);

  const float4 w4 = *(const float4*)&fnw[c];
  const float sv[4] = {s.x,s.y,s.z,s.w};
  const float wv4[4] = {w4.x,w4.y,w4.z,w4.w};
  float hm[4];
  float lg[4] = {0.f,0.f,0.f,0.f};
  #pragma unroll
  for (int j=0;j<4;++j){
    hm[j] = sv[j]*rstd*wv4[j];
    st_sp<SPLIT>(hhi, hlo, (size_t)t*Dm + c + j, hm[j]);
    const float4 r4 = *(const float4*)&rw[(size_t)(c+j)*4];
    lg[0] += hm[j]*r4.x; lg[1] += hm[j]*r4.y; lg[2] += hm[j]*r4.z; lg[3] += hm[j]*r4.w;
  }
  #pragma unroll
  for (int d=1; d<64; d<<=1){
    lg[0]+=__shfl_xor(lg[0],d); lg[1]+=__shfl_xor(lg[1],d);
    lg[2]+=__shfl_xor(lg[2],d); lg[3]+=__shfl_xor(lg[3],d);
  }
  __shared__ float red2[4][4];
  if (lane==0){ red2[wv][0]=lg[0]; red2[wv][1]=lg[1]; red2[wv][2]=lg[2]; red2[wv][3]=lg[3]; }
  __syncthreads();
  if (tid==0){
    float L[4];
    #pragma unroll
    for (int e=0;e<4;++e) L[e] = red2[0][e]+red2[1][e]+red2[2][e]+red2[3][e];
    int s0 = 0;
    for (int e=1;e<4;++e) if (L[e] > L[s0]) s0 = e;
    int s1 = -1;
    for (int e=0;e<4;++e){ if (e==s0) continue; if (s1<0 || L[e] > L[s1]) s1 = e; }
    const float eb2 = expf(L[s1] - L[s0]);
    const float inv = 1.0f/(1.0f + eb2);
    float o[4] = {0.f,0.f,0.f,0.f};
    o[s0] = inv; o[s1] = eb2*inv;
    cmb[t*4+0]=o[0]; cmb[t*4+1]=o[1]; cmb[t*4+2]=o[2]; cmb[t*4+3]=o[3];
  }
}

// fused: x += moe(part, cmb) ; optional x write ; rms(w)->SPLIT1 planes
__global__ __launch_bounds__(256) void k_fuse_moe(
    const float* __restrict__ part, const float* __restrict__ cmb,
    const float* __restrict__ w, float* __restrict__ x,
    unsigned short* __restrict__ dst, int writex)
{
  const int t = blockIdx.x, tid = threadIdx.x, wv = tid>>6, lane = tid&63;
  const int c = tid*4;
  float4 s = *(float4*)&x[(size_t)t*Dm + c];
  #pragma unroll
  for (int e=0; e<4; ++e){
    if (cmb[(size_t)t*4 + e] > 0.f){
      const float4 p0 = *(const float4*)&part[((size_t)(e*2+0)*NT + t)*Dm + c];
      const float4 p1 = *(const float4*)&part[((size_t)(e*2+1)*NT + t)*Dm + c];
      s.x+=p0.x+p1.x; s.y+=p0.y+p1.y; s.z+=p0.z+p1.z; s.w+=p0.w+p1.w;
    }
  }
  if (writex) *(float4*)&x[(size_t)t*Dm + c] = s;
  float ss = s.x*s.x + s.y*s.y + s.z*s.z + s.w*s.w;
  #pragma unroll
  for (int d=1; d<64; d<<=1) ss += __shfl_xor(ss, d);
  __shared__ float red[4];
  if (lane==0) red[wv] = ss;
  __syncthreads();
  const float rstd = rsqrtf((red[0]+red[1]+red[2]+red[3])*(1.0f/Dm) + EPSf);
  const float4 w4 = *(const float4*)&w[c];
  const float sv[4] = {s.x,s.y,s.z,s.w};
  const float wv4[4] = {w4.x,w4.y,w4.z,w4.w};
  #pragma unroll
  for (int j=0;j<4;++j)
    dst[(size_t)t*Dm + c + j] = h2u((_Float16)(sv[j]*rstd*wv4[j]));
}

// transpose+split tile converter (64x64)
template<int SPLIT>
DEV void wconv_tile(const float* __restrict__ W, unsigned short* __restrict__ Whi,
                    unsigned short* __restrict__ Wlo, int K, int N, int n0, int k0,
                    float (*tile)[65], int t)
{
  const int r = t>>2;
  #pragma unroll
  for (int i=0;i<4;++i){
    const int c = (t&3)*16 + i*4;
    *(float4*)&tile[r][c] = *(const float4*)&W[(size_t)(k0+r)*N + n0 + c];
  }
  __syncthreads();
  const int n = t>>2;
  #pragma unroll
  for (int i=0;i<2;++i){
    const int kc = (t&3)*8 + i*32;
    u16x8 hi, lo;
    #pragma unroll
    for (int j=0;j<8;++j){
      const float v = tile[kc+j][n];
      const _Float16 hh = (_Float16)v;
      hi[j] = h2u(hh);
      if constexpr (SPLIT==3) lo[j] = h2u((_Float16)((v-(float)hh)*LOSC));
      else lo[j] = 0;
    }
    *(u16x8*)&Whi[(size_t)(n0+n)*K + k0 + kc] = hi;
    if constexpr (SPLIT==3) *(u16x8*)&Wlo[(size_t)(n0+n)*K + k0 + kc] = lo;
  }
}

template<int SPLIT>
__global__ __launch_bounds__(256) void k_wconv(
    const float* __restrict__ W, unsigned short* __restrict__ Whi,
    unsigned short* __restrict__ Wlo, int K, int N)
{
  __shared__ float tile[64][65];
  const size_t eb = (size_t)blockIdx.z * (size_t)K * N;
  wconv_tile<SPLIT>(W + eb, Whi + eb, Wlo + eb, K, N, blockIdx.x*64, blockIdx.y*64,
                    tile, threadIdx.x);
}

template<int SPLIT>
__global__ __launch_bounds__(256) void k_wconv_qkvo(
    const float* __restrict__ qw, const float* __restrict__ kvw, const float* __restrict__ ow,
    unsigned short* __restrict__ Wh, unsigned short* __restrict__ Wl,
    unsigned short* __restrict__ WOh, unsigned short* __restrict__ WOl)
{
  __shared__ float tile[64][65];
  const int b = blockIdx.x, t = threadIdx.x;
  if (b < 256){
    wconv_tile<SPLIT>(qw, Wh, Wl, Dm, Dm, (b&15)*64, (b>>4)*64, tile, t);
  } else if (b < 768){
    const int c = b - 256;
    wconv_tile<SPLIT>(kvw, Wh + (size_t)Dm*Dm, Wl + (size_t)Dm*Dm,
                      Dm, 2*Dm, (c&31)*64, (c>>5)*64, tile, t);
  } else {
    const int c = b - 768;
    wconv_tile<SPLIT>(ow, WOh, WOl, Dm, Dm, (c&15)*64, (c>>4)*64, tile, t);
  }
}

// merged gate+up weight conversion + expert scan (block 4096)
template<int SPLIT>
__global__ __launch_bounds__(256) void k_wconv_gu(
    const float* __restrict__ gw, const float* __restrict__ uw,
    unsigned short* __restrict__ WGh, unsigned short* __restrict__ WGl,
    unsigned short* __restrict__ WUh, unsigned short* __restrict__ WUl,
    const float* __restrict__ cmb, int* __restrict__ tl,
    float* __restrict__ cwl, int* __restrict__ cnt)
{
  __shared__ float tile[64][65];
  const int b = blockIdx.x, t = threadIdx.x;
  if (b >= 4096){
    const int e = t>>6, lane = t&63;
    int base = 0;
    for (int t0=0; t0<NT; t0+=64){
      const float w = cmb[(size_t)(t0+lane)*4 + e];
      const unsigned long long m = __ballot(w > 0.f);
      const int pre = __popcll(m & ((1ull<<lane)-1ull));
      if (w > 0.f){ tl[e*NT + base + pre] = t0+lane; cwl[e*NT + base + pre] = w; }
      base += __popcll(m);
    }
    if (lane==0) cnt[e] = base;
    return;
  }
  const int half = b >> 11;
  const int c = b & 2047;
  const int e = c >> 9, cc = c & 511;
  const size_t eb = (size_t)e * (size_t)Dm * HIDm;
  const int n0 = (cc&31)*64, k0 = (cc>>5)*64;
  if (half == 0)
    wconv_tile<SPLIT>(gw + eb, WGh + eb, WGl + eb, Dm, HIDm, n0, k0, tile, t);
  else
    wconv_tile<SPLIT>(uw + eb, WUh + eb, WUl + eb, Dm, HIDm, n0, k0, tile, t);
}

// 128x128-tile GEMM, f32 partial-store epilogue. ZMODE: 2 = K-chunk (koff=zz*K)
template<int SPLIT, int ZMODE>
__global__ __launch_bounds__(256) void k_mm(
    const unsigned short* __restrict__ Ahi, const unsigned short* __restrict__ Alo,
    const unsigned short* __restrict__ Bhi, const unsigned short* __restrict__ Blo,
    float* __restrict__ part, int lda, int ldb, int K, int ldo)
{
  constexpr int PL = (SPLIT==3)?2:1;
  __shared__ __align__(16) unsigned short As[PL][128][32];
  __shared__ __align__(16) unsigned short Bs[PL][128][32];
  const int tid=threadIdx.x, wv=tid>>6, lane=tid&63, fr=lane&15, fg=lane>>4;
  const int n0=blockIdx.x*128, r0=blockIdx.y*128, zz=blockIdx.z;
  const int wr=(wv>>1)*64, wc=(wv&1)*64;
  const int sr=lane>>2, sk=swk(lane);
  const int rc = rdc(fr, fg);

  const f32x4 z4={0.f,0.f,0.f,0.f};
  f32x4 accM[4][4], accC[4][4];
  #pragma unroll
  for (int i=0;i<4;++i)
    #pragma unroll
    for (int j=0;j<4;++j){ accM[i][j]=z4; accC[i][j]=z4; }

  for (int kt=0; kt<K; kt+=32){
    #pragma unroll
    for (int i=0;i<2;++i){
      const int rr = wv*32 + i*16 + sr;
      size_t ao, bo;
      if constexpr (ZMODE==2){
        ao = (size_t)(r0+rr)*lda + zz*K + kt + sk;
        bo = (size_t)(n0+rr)*ldb + zz*K + kt + sk;
      } else {
        ao = (size_t)(r0+rr)*lda + kt + sk;
        bo = (size_t)(n0+rr)*ldb + kt + sk;
      }
      gll16(&Ahi[ao], &As[0][wv*32+i*16][0]);
      if constexpr (SPLIT==3) gll16(&Alo[ao], &As[1][wv*32+i*16][0]);
      gll16(&Bhi[bo], &Bs[0][wv*32+i*16][0]);
      if constexpr (SPLIT==3) gll16(&Blo[bo], &Bs[1][wv*32+i*16][0]);
    }
    __syncthreads();
    f16x8 a[4][PL], b[4][PL];
    #pragma unroll
    for (int rt=0;rt<4;++rt)
      #pragma unroll
      for (int p=0;p<PL;++p) a[rt][p] = *(const f16x8*)&As[p][wr+rt*16+fr][rc];
    #pragma unroll
    for (int ct=0;ct<4;++ct)
      #pragma unroll
      for (int p=0;p<PL;++p) b[ct][p] = *(const f16x8*)&Bs[p][wc+ct*16+fr][rc];
    #pragma unroll
    for (int rt=0;rt<4;++rt)
      #pragma unroll
      for (int ct=0;ct<4;++ct){
        accM[rt][ct] = MF(a[rt][0], b[ct][0], accM[rt][ct]);
        if constexpr (SPLIT==3){
          accC[rt][ct] = MF(a[rt][0], b[ct][1], accC[rt][ct]);
          accC[rt][ct] = MF(a[rt][1], b[ct][0], accC[rt][ct]);
        }
      }
    __syncthreads();
  }

  #pragma unroll
  for (int rt=0;rt<4;++rt)
    #pragma unroll
    for (int ct=0;ct<4;++ct)
      #pragma unroll
      for (int j=0;j<4;++j){
        const int row = r0 + wr + rt*16 + fg*4 + j;
        const int col = n0 + wc + ct*16 + fr;
        float v = accM[rt][ct][j];
        if constexpr (SPLIT==3) v += accC[rt][ct][j]*ILOSC;
        part[((size_t)zz*NT + row)*ldo + col] = v;
      }
}

// merged qkv combine: bid<1024 -> q/k rows; else v transpose tiles
template<int SPLIT>
__global__ __launch_bounds__(256) void k_comb_qkvt(
    const float* __restrict__ part, const float* __restrict__ qb, const float* __restrict__ kvb,
    unsigned short* __restrict__ qhi, unsigned short* __restrict__ qlo,
    unsigned short* __restrict__ khi, unsigned short* __restrict__ klo,
    unsigned short* __restrict__ vthi, unsigned short* __restrict__ vtlo)
{
  __shared__ float tile[64][65];
  const int bid = blockIdx.x, tid = threadIdx.x;
  if (bid < 1024){
    const int t = bid;
    #pragma unroll
    for (int i=0;i<2;++i){
      const int col = tid*4 + i*1024;
      const float4 p0 = *(const float4*)&part[(size_t)t*3072 + col];
      const float4 p1 = *(const float4*)&part[((size_t)NT + t)*3072 + col];
      float v[4] = {p0.x+p1.x, p0.y+p1.y, p0.z+p1.z, p0.w+p1.w};
      #pragma unroll
      for (int j=0;j<4;++j){
        const int c = col + j;
        if (c < Dm) st_sp<SPLIT>(qhi, qlo, (size_t)t*Dm + c, v[j] + qb[c]);
        else        st_sp<SPLIT>(khi, klo, (size_t)t*Dm + (c-Dm), v[j] + kvb[c-Dm]);
      }
    }
  } else {
    const int c = bid - 1024;
    const int d0 = (c&15)*64, t0 = (c>>4)*64;
    {
      const int tl_ = tid>>2, dc = (tid&3)*16;
      #pragma unroll
      for (int i=0;i<4;++i){
        const int d = dc + i*4;
        const float4 p0 = *(const float4*)&part[(size_t)(t0+tl_)*3072 + 2048 + d0 + d];
        const float4 p1 = *(const float4*)&part[((size_t)NT + t0+tl_)*3072 + 2048 + d0 + d];
        tile[tl_][d+0] = p0.x+p1.x + kvb[1024+d0+d+0];
        tile[tl_][d+1] = p0.y+p1.y + kvb[1024+d0+d+1];
        tile[tl_][d+2] = p0.z+p1.z + kvb[1024+d0+d+2];
        tile[tl_][d+3] = p0.w+p1.w + kvb[1024+d0+d+3];
      }
    }
    __syncthreads();
    #pragma unroll
    for (int i=0;i<2;++i){
      const int u = tid + i*256;
      const int dl = u>>3, tch = (u&7)*8;
      u16x8 hi, lo;
      #pragma unroll
      for (int j=0;j<8;++j){
        const float v = tile[tch+j][dl];
        const _Float16 hh = (_Float16)v;
        hi[j] = h2u(hh);
        if constexpr (SPLIT==3) lo[j] = h2u((_Float16)((v-(float)hh)*LOSC));
        else lo[j] = 0;
      }
      *(u16x8*)&vthi[(size_t)(d0+dl)*NT + t0 + tch] = hi;
      if constexpr (SPLIT==3) *(u16x8*)&vtlo[(size_t)(d0+dl)*NT + t0 + tch] = lo;
    }
  }
}

// sparse down-proj, K split in 2: z = e*2+ks; scatter to part[e*2+ks][token]
template<int SPLIT>
__global__ __launch_bounds__(256) void k_down(
    const unsigned short* __restrict__ Ahi, const unsigned short* __restrict__ Alo,
    const unsigned short* __restrict__ Bhi, const unsigned short* __restrict__ Blo,
    const int* __restrict__ tl, const int* __restrict__ cnt,
    float* __restrict__ part)
{
  constexpr int PL = (SPLIT==3)?2:1;
  const int zz = blockIdx.z, e = zz>>1, ks = zz&1;
  const int r0 = blockIdx.y*128, n0 = blockIdx.x*128;
  const int cn = cnt[e];
  if (r0 >= cn) return;
  __shared__ __align__(16) unsigned short As[PL][128][32];
  __shared__ __align__(16) unsigned short Bs[PL][128][32];
  __shared__ int tl_s[128];
  const int tid=threadIdx.x, wv=tid>>6, lane=tid&63, fr=lane&15, fg=lane>>4;
  const int wr=(wv>>1)*64, wc=(wv&1)*64;
  const int sr=lane>>2, sk=swk(lane);
  const int rc = rdc(fr, fg);
  if (tid < 128) tl_s[tid] = (r0+tid < cn) ? tl[e*NT + r0 + tid] : -1;

  const f32x4 z4={0.f,0.f,0.f,0.f};
  f32x4 accM[4][4], accC[4][4];
  #pragma unroll
  for (int i=0;i<4;++i)
    #pragma unroll
    for (int j=0;j<4;++j){ accM[i][j]=z4; accC[i][j]=z4; }

  const int kbeg = ks*1024, kend = kbeg + 1024;
  for (int kt=kbeg; kt<kend; kt+=32){
    #pragma unroll
    for (int i=0;i<2;++i){
      const int rr = wv*32 + i*16 + sr;
      const size_t ao = (size_t)((e<<10) + r0 + rr)*HIDm + kt + sk;
      const size_t bo = (size_t)e*((size_t)Dm*HIDm) + (size_t)(n0+rr)*HIDm + kt + sk;
      gll16(&Ahi[ao], &As[0][wv*32+i*16][0]);
      if constexpr (SPLIT==3) gll16(&Alo[ao], &As[1][wv*32+i*16][0]);
      gll16(&Bhi[bo], &Bs[0][wv*32+i*16][0]);
      if constexpr (SPLIT==3) gll16(&Blo[bo], &Bs[1][wv*32+i*16][0]);
    }
    __syncthreads();
    f16x8 a[4][PL], b[4][PL];
    #pragma unroll
    for (int rt=0;rt<4;++rt)
      #pragma unroll
      for (int p=0;p<PL;++p) a[rt][p] = *(const f16x8*)&As[p][wr+rt*16+fr][rc];
    #pragma unroll
    for (int ct=0;ct<4;++ct)
      #pragma unroll
      for (int p=0;p<PL;++p) b[ct][p] = *(const f16x8*)&Bs[p][wc+ct*16+fr][rc];
    #pragma unroll
    for (int rt=0;rt<4;++rt)
      #pragma unroll
      for (int ct=0;ct<4;++ct){
        accM[rt][ct] = MF(a[rt][0], b[ct][0], accM[rt][ct]);
        if constexpr (SPLIT==3){
          accC[rt][ct] = MF(a[rt][0], b[ct][1], accC[rt][ct]);
          accC[rt][ct] = MF(a[rt][1], b[ct][0], accC[rt][ct]);
        }
      }
    __syncthreads();
  }

  #pragma unroll
  for (int rt=0;rt<4;++rt)
    #pragma unroll
    for (int ct=0;ct<4;++ct)
      #pragma unroll
      for (int j=0;j<4;++j){
        const int i = wr + rt*16 + fg*4 + j;
        const int col = n0 + wc + ct*16 + fr;
        float v = accM[rt][ct][j];
        if constexpr (SPLIT==3) v += accC[rt][ct][j]*ILOSC;
        const int tok = tl_s[i];
        if (tok >= 0) part[((size_t)zz*NT + tok)*Dm + col] = v;
      }
}

// sparse fused gate/up GEMM v3: 256 threads (4 waves 2Mx2N), tile 64(M)x64(N),
// 3D grid (32, 16, 4) — finer M granularity doubles active blocks/CU.
template<int SPLIT>
__global__ __launch_bounds__(256) void k_guf(
    const unsigned short* __restrict__ Ahi, const unsigned short* __restrict__ Alo,
    const unsigned short* __restrict__ Ghi, const unsigned short* __restrict__ Glo,
    const unsigned short* __restrict__ Uhi, const unsigned short* __restrict__ Ulo,
    const int* __restrict__ tl, const float* __restrict__ cwl, const int* __restrict__ cnt,
    unsigned short* __restrict__ Hhi, unsigned short* __restrict__ Hlo, float scale)
{
  constexpr int PL=(SPLIT==3)?2:1;
  const int e = blockIdx.z, r0 = blockIdx.y*64, n0 = blockIdx.x*64;
  const int cn = cnt[e];
  if (r0 >= cn) return;
  __shared__ __align__(16) unsigned short As[PL][64][32];
  __shared__ __align__(16) unsigned short Gs[PL][64][32];
  __shared__ __align__(16) unsigned short Us[PL][64][32];
  __shared__ float cw_s[64];
  const int tid=threadIdx.x, wv=tid>>6, lane=tid&63, fr=lane&15, fg=lane>>4;
  const int wr=(wv>>1)*32, wc=(wv&1)*32;
  const int sr=lane>>2, sk=swk(lane);
  const int rc = rdc(fr, fg);
  const size_t ebW = (size_t)e * ((size_t)HIDm*Dm);
  if (tid < 64) cw_s[tid] = (r0+tid < cn) ? cwl[e*NT + r0 + tid]*scale : 0.f;

  const int lrA = r0 + wv*16 + sr;
  const int tokA = tl[e*NT + (lrA < cn ? lrA : cn-1)];
  const size_t abase = (size_t)tokA*Dm + sk;
  const int rrB = wv*16 + sr;
  const size_t bbase = ebW + (size_t)(n0+rrB)*Dm + sk;

  const f32x4 z4={0.f,0.f,0.f,0.f};
  f32x4 aGM[2][2],aGC[2][2],aUM[2][2],aUC[2][2];
  #pragma unroll
  for (int i=0;i<2;++i)
    #pragma unroll
    for (int j=0;j<2;++j){ aGM[i][j]=z4; aGC[i][j]=z4; aUM[i][j]=z4; aUC[i][j]=z4; }

  for (int kt=0; kt<Dm; kt+=32){
    gll16(&Ahi[abase + kt], &As[0][wv*16][0]);
    if constexpr (SPLIT==3) gll16(&Alo[abase + kt], &As[1][wv*16][0]);
    gll16(&Ghi[bbase + kt], &Gs[0][wv*16][0]);
    gll16(&Uhi[bbase + kt], &Us[0][wv*16][0]);
    if constexpr (SPLIT==3){
      gll16(&Glo[bbase + kt], &Gs[1][wv*16][0]);
      gll16(&Ulo[bbase + kt], &Us[1][wv*16][0]);
    }
    __syncthreads();
    f16x8 a[2][PL], bg[2][PL], bu[2][PL];
    #pragma unroll
    for (int rt=0;rt<2;++rt)
      #pragma unroll
      for (int p=0;p<PL;++p) a[rt][p] = *(const f16x8*)&As[p][wr+rt*16+fr][rc];
    #pragma unroll
    for (int ct=0;ct<2;++ct)
      #pragma unroll
      for (int p=0;p<PL;++p){
        bg[ct][p] = *(const f16x8*)&Gs[p][wc+ct*16+fr][rc];
        bu[ct][p] = *(const f16x8*)&Us[p][wc+ct*16+fr][rc];
      }
    #pragma unroll
    for (int rt=0;rt<2;++rt)
      #pragma unroll
      for (int ct=0;ct<2;++ct){
        aGM[rt][ct] = MF(a[rt][0], bg[ct][0], aGM[rt][ct]);
        aUM[rt][ct] = MF(a[rt][0], bu[ct][0], aUM[rt][ct]);
        if constexpr (SPLIT==3){
          aGC[rt][ct] = MF(a[rt][0], bg[ct][1], aGC[rt][ct]);
          aGC[rt][ct] = MF(a[rt][1], bg[ct][0], aGC[rt][ct]);
          aUC[rt][ct] = MF(a[rt][0], bu[ct][1], aUC[rt][ct]);
          aUC[rt][ct] = MF(a[rt][1], bu[ct][0], aUC[rt][ct]);
        }
      }
    __syncthreads();
  }
  #pragma unroll
  for (int rt=0;rt<2;++rt)
    #pragma unroll
    for (int ct=0;ct<2;++ct)
      #pragma unroll
      for (int j=0;j<4;++j){
        const int i = wr + rt*16 + fg*4 + j;
        const int row = r0 + i;
        const int col = n0 + wc + ct*16 + fr;
        float g2 = aGM[rt][ct][j], u = aUM[rt][ct][j];
        if constexpr (SPLIT==3){ g2 += aGC[rt][ct][j]*ILOSC; u += aUC[rt][ct][j]*ILOSC; }
        const float cw = cw_s[i];
        const float h = (g2/(1.0f + expf(-g2))) * u * cw;
        st_sp<SPLIT>(Hhi, Hlo, (size_t)((e<<10) + row)*HIDm + col, h);
      }
}

// logits GEMM, fallback: in-kernel B convert, BK=32
__global__ __launch_bounds__(256) void k_lg(
    const unsigned short* __restrict__ Ahi, const float* __restrict__ emb,
    float* __restrict__ out)
{
  __shared__ __align__(16) unsigned short As[128][32];
  __shared__ __align__(16) unsigned short Bs[128][32];
  const int tid=threadIdx.x, wv=tid>>6, lane=tid&63, fr=lane&15, fg=lane>>4;
  const int w = (blockIdx.x & 7)*250 + (blockIdx.x >> 3);
  const int n0 = (w>>3)*128, r0 = (w&7)*128;
  const int wr=(wv>>1)*64, wc=(wv&1)*64;
  const int sr=lane>>2, sk=swk(lane);
  const int rc = rdc(fr, fg);
  const int br = tid>>1;
  const f32x4 z4={0.f,0.f,0.f,0.f};
  f32x4 acc[4][4];
  #pragma unroll
  for (int i=0;i<4;++i)
    #pragma unroll
    for (int j=0;j<4;++j) acc[i][j]=z4;

  for (int kt=0; kt<Dm; kt+=32){
    #pragma unroll
    for (int i=0;i<2;++i){
      const int rr = wv*32 + i*16 + sr;
      gll16(&Ahi[(size_t)(r0+rr)*Dm + kt + sk], &As[wv*32+i*16][0]);
    }
    {
      const int bc = (tid&1)*16;
      const float* s = &emb[(size_t)(n0+br)*Dm + kt + bc];
      const float4 v0 = *(const float4*)s;
      const float4 v1 = *(const float4*)(s+4);
      const float4 v2 = *(const float4*)(s+8);
      const float4 v3 = *(const float4*)(s+12);
      u16x8 h0, h1;
      h0[0]=h2u((_Float16)v0.x); h0[1]=h2u((_Float16)v0.y);
      h0[2]=h2u((_Float16)v0.z); h0[3]=h2u((_Float16)v0.w);
      h0[4]=h2u((_Float16)v1.x); h0[5]=h2u((_Float16)v1.y);
      h0[6]=h2u((_Float16)v1.z); h0[7]=h2u((_Float16)v1.w);
      h1[0]=h2u((_Float16)v2.x); h1[1]=h2u((_Float16)v2.y);
      h1[2]=h2u((_Float16)v2.z); h1[3]=h2u((_Float16)v2.w);
      h1[4]=h2u((_Float16)v3.x); h1[5]=h2u((_Float16)v3.y);
      h1[6]=h2u((_Float16)v3.z); h1[7]=h2u((_Float16)v3.w);
      const int s_ = (br>>1)&3;
      const int u0 = (tid&1)*2;
      *(u16x8*)&Bs[br][(u0^s_)*8]     = h0;
      *(u16x8*)&Bs[br][((u0+1)^s_)*8] = h1;
    }
    __syncthreads();
    f16x8 a[4], b[4];
    #pragma unroll
    for (int rt=0;rt<4;++rt) a[rt] = *(const f16x8*)&As[wr+rt*16+fr][rc];
    #pragma unroll
    for (int ct=0;ct<4;++ct) b[ct] = *(const f16x8*)&Bs[wc+ct*16+fr][rc];
    #pragma unroll
    for (int rt=0;rt<4;++rt)
      #pragma unroll
      for (int ct=0;ct<4;++ct) acc[rt][ct] = MF(a[rt], b[ct], acc[rt][ct]);
    __syncthreads();
  }
  #pragma unroll
  for (int rt=0;rt<4;++rt)
    #pragma unroll
    for (int ct=0;ct<4;++ct)
      #pragma unroll
      for (int j=0;j<4;++j)
        out[(size_t)(r0+wr+rt*16+fg*4+j)*NV + n0+wc+ct*16+fr] = acc[rt][ct][j];
}

// logits GEMM fast path (R11-proven): 256x256 tile, 512 threads (8 waves 2Mx4N),
// BK=64, row&7-XOR unit swizzle, bijective XCD swizzle for 500 blocks
__global__ __launch_bounds__(512) void k_lg16(
    const unsigned short* __restrict__ Ahi, const unsigned short* __restrict__ B16,
    float* __restrict__ out)
{
  __shared__ __align__(16) unsigned short As[256][64];
  __shared__ __align__(16) unsigned short Bs[256][64];
  const int tid=threadIdx.x, wv=tid>>6, lane=tid&63, fr=lane&15, fg=lane>>4;
  const int xcd = blockIdx.x & 7, ii = blockIdx.x >> 3;
  const int w = (xcd < 4 ? xcd*63 : 252 + (xcd-4)*62) + ii;   // bijective, 500=4*63+4*62
  const int n0 = (w>>2)*256, r0 = (w&3)*256;
  const int wrow=(wv>>2)*128, wcol=(wv&3)*64;
  const int srow = lane>>3;
  const int sk = (((lane&7) ^ srow)*8);
  const f32x4 z4={0.f,0.f,0.f,0.f};
  f32x4 acc[8][4];
  #pragma unroll
  for (int i=0;i<8;++i)
    #pragma unroll
    for (int j=0;j<4;++j) acc[i][j]=z4;

  for (int kt=0; kt<Dm; kt+=64){
    #pragma unroll
    for (int i=0;i<4;++i){
      const int rr = wv*32 + i*8 + srow;
      gll16(&Ahi[(size_t)(r0+rr)*Dm + kt + sk], &As[wv*32+i*8][0]);
      gll16(&B16[(size_t)(n0+rr)*Dm + kt + sk], &Bs[wv*32+i*8][0]);
    }
    __syncthreads();
    #pragma unroll
    for (int kk=0;kk<2;++kk){
      f16x8 a[8], b[4];
      #pragma unroll
      for (int rt=0;rt<8;++rt)
        a[rt] = *(const f16x8*)&As[wrow+rt*16+fr][(((kk*4+fg) ^ (fr&7))*8)];
      #pragma unroll
      for (int ct=0;ct<4;++ct)
        b[ct] = *(const f16x8*)&Bs[wcol+ct*16+fr][(((kk*4+fg) ^ (fr&7))*8)];
      #pragma unroll
      for (int rt=0;rt<8;++rt)
        #pragma unroll
        for (int ct=0;ct<4;++ct) acc[rt][ct] = MF(a[rt], b[ct], acc[rt][ct]);
    }
    __syncthreads();
  }
  #pragma unroll
  for (int rt=0;rt<8;++rt)
    #pragma unroll
    for (int ct=0;ct<4;++ct)
      #pragma unroll
      for (int j=0;j<4;++j)
        out[(size_t)(r0+wrow+rt*16+fg*4+j)*NV + n0+wcol+ct*16+fr] = acc[rt][ct][j];
}

// flash-style attention v3: 4-wave blocks, intra-block flash split-K
// (wave w handles k-tiles kt%4==w; LSE merge tree), longest-first dispatch.
template<int SPLIT>
__global__ __launch_bounds__(256) void k_attn(
    const unsigned short* __restrict__ qhi, const unsigned short* __restrict__ qlo,
    const unsigned short* __restrict__ khi, const unsigned short* __restrict__ klo,
    const unsigned short* __restrict__ vthi, const unsigned short* __restrict__ vtlo,
    unsigned short* __restrict__ yhi, unsigned short* __restrict__ ylo)
{
  constexpr int PL = (SPLIT==3) ? 2 : 1;
  const int qt = (int)gridDim.x - 1 - (int)blockIdx.x;   // longest blocks first
  const int hd = blockIdx.y;
  const int tid = threadIdx.x, wv = tid>>6, lane = tid&63;
  const int fr = lane&15, fg = lane>>4;
  const int rbase = qt*16;
  const float slope = (float)(hd+1) * (1.0f/16.0f);

  __shared__ __align__(16) unsigned short Ps[4][PL][16][32];
  __shared__ float Lm[3][64][4], Ll[3][64][4];
  __shared__ float LyM[3][64][16];
  __shared__ float LyC[(SPLIT==3)?3:1][64][16];

  f16x8 aq[2][PL];
  #pragma unroll
  for (int c=0;c<2;++c){
    const size_t off = (size_t)(rbase+fr)*Dm + hd*64 + c*32 + fg*8;
    aq[c][0] = *(const f16x8*)&qhi[off];
    if constexpr (SPLIT==3) aq[c][1] = *(const f16x8*)&qlo[off];
  }

  const f32x4 z4 = {0.f,0.f,0.f,0.f};
  f32x4 yM[4], yC[4];
  #pragma unroll
  for (int ct=0;ct<4;++ct){ yM[ct]=z4; yC[ct]=z4; }
  float m[4], lsum[4];
  #pragma unroll
  for (int j=0;j<4;++j){ m[j] = -INFINITY; lsum[j] = 0.f; }

  const int nkt = qt/2 + 1;
  for (int kt=wv; kt<nkt; kt+=4){
    f32x4 sM[2], sC[2];
    sM[0]=z4; sM[1]=z4; sC[0]=z4; sC[1]=z4;
    #pragma unroll
    for (int kh=0; kh<2; ++kh){
      #pragma unroll
      for (int c=0;c<2;++c){
        const size_t off = (size_t)(kt*32 + kh*16 + fr)*Dm + hd*64 + c*32 + fg*8;
        const f16x8 b0 = *(const f16x8*)&khi[off];
        sM[kh] = MF(aq[c][0], b0, sM[kh]);
        if constexpr (SPLIT==3){
          const f16x8 b1 = *(const f16x8*)&klo[off];
          sC[kh] = MF(aq[c][0], b1, sC[kh]);
          sC[kh] = MF(aq[c][1], b0, sC[kh]);
        }
      }
    }
    float sv[2][4], mx[4];
    #pragma unroll
    for (int j=0;j<4;++j) mx[j] = -INFINITY;
    #pragma unroll
    for (int kh=0; kh<2; ++kh)
      #pragma unroll
      for (int j=0;j<4;++j){
        const int kcol = kt*32 + kh*16 + fr;
        const int row  = rbase + fg*4 + j;
        float s = sM[kh][j];
        if constexpr (SPLIT==3) s += sC[kh][j]*ILOSC;
        s = s*0.125f + slope*(float)(kcol - row);
        sv[kh][j] = (kcol > row) ? -INFINITY : s;
        mx[j] = fmaxf(mx[j], sv[kh][j]);
      }
    #pragma unroll
    for (int d=1; d<16; d<<=1)
      #pragma unroll
      for (int j=0;j<4;++j) mx[j] = fmaxf(mx[j], __shfl_xor(mx[j], d));
    float resc[4];
    #pragma unroll
    for (int j=0;j<4;++j){
      const float mn = fmaxf(m[j], mx[j]);
      resc[j] = expf(m[j] - mn);
      m[j] = mn;
    }
    float p[2][4], psum[4];
    #pragma unroll
    for (int j=0;j<4;++j) psum[j] = 0.f;
    #pragma unroll
    for (int kh=0;kh<2;++kh)
      #pragma unroll
      for (int j=0;j<4;++j){
        const float pv = (sv[kh][j] == -INFINITY) ? 0.f : expf(sv[kh][j] - m[j]);
        p[kh][j] = pv; psum[j] += pv;
      }
    #pragma unroll
    for (int d=1; d<16; d<<=1)
      #pragma unroll
      for (int j=0;j<4;++j) psum[j] += __shfl_xor(psum[j], d);
    #pragma unroll
    for (int j=0;j<4;++j) lsum[j] = lsum[j]*resc[j] + psum[j];
    #pragma unroll
    for (int ct=0;ct<4;++ct)
      #pragma unroll
      for (int j=0;j<4;++j){ yM[ct][j]*=resc[j]; yC[ct][j]*=resc[j]; }
    #pragma unroll
    for (int kh=0;kh<2;++kh)
      #pragma unroll
      for (int j=0;j<4;++j){
        const float pv = p[kh][j];
        _Float16 ph = (_Float16)pv;
        Ps[wv][0][fg*4+j][kh*16+fr] = h2u(ph);
        if constexpr (SPLIT==3)
          Ps[wv][1][fg*4+j][kh*16+fr] = h2u((_Float16)((pv-(float)ph)*LOSC));
      }
    asm volatile("s_waitcnt lgkmcnt(0)" ::: "memory");
    f16x8 pa[PL];
    pa[0] = *(const f16x8*)&Ps[wv][0][fr][fg*8];
    if constexpr (SPLIT==3) pa[1] = *(const f16x8*)&Ps[wv][1][fr][fg*8];
    #pragma unroll
    for (int ct=0;ct<4;++ct){
      const size_t off = (size_t)(hd*64 + ct*16 + fr)*NT + kt*32 + fg*8;
      const f16x8 v0 = *(const f16x8*)&vthi[off];
      yM[ct] = MF(pa[0], v0, yM[ct]);
      if constexpr (SPLIT==3){
        const f16x8 v1 = *(const f16x8*)&vtlo[off];
        yC[ct] = MF(pa[0], v1, yC[ct]);
        yC[ct] = MF(pa[1], v0, yC[ct]);
      }
    }
    asm volatile("s_waitcnt lgkmcnt(0)" ::: "memory");
  }

  // LSE merge: waves 1..3 publish state, wave0 folds them in and stores.
  if (wv > 0){
    const int s = wv - 1;
    #pragma unroll
    for (int j=0;j<4;++j){ Lm[s][lane][j] = m[j]; Ll[s][lane][j] = lsum[j]; }
    #pragma unroll
    for (int ct=0;ct<4;++ct)
      #pragma unroll
      for (int j=0;j<4;++j){
        LyM[s][lane][ct*4+j] = yM[ct][j];
        if constexpr (SPLIT==3) LyC[s][lane][ct*4+j] = yC[ct][j];
      }
  }
  __syncthreads();
  if (wv == 0){
    #pragma unroll
    for (int s=0; s<3; ++s){
      #pragma unroll
      for (int j=0;j<4;++j){
        const float m1 = Lm[s][lane][j];
        const float M  = fmaxf(m[j], m1);
        const float a0 = expf(m[j] - M);   // m[j] finite (tile 0 is wave0's)
        const float a1 = expf(m1 - M);     // exp(-inf)=0 when wave s+1 idle
        lsum[j] = lsum[j]*a0 + Ll[s][lane][j]*a1;
        #pragma unroll
        for (int ct=0;ct<4;++ct){
          yM[ct][j] = yM[ct][j]*a0 + LyM[s][lane][ct*4+j]*a1;
          if constexpr (SPLIT==3) yC[ct][j] = yC[ct][j]*a0 + LyC[s][lane][ct*4+j]*a1;
        }
        m[j] = M;
      }
    }
    #pragma unroll
    for (int ct=0;ct<4;++ct)
      #pragma unroll
      for (int j=0;j<4;++j){
        float v = yM[ct][j];
        if constexpr (SPLIT==3) v += yC[ct][j]*ILOSC;
        v /= lsum[j];
        const size_t off = (size_t)(rbase + fg*4 + j)*Dm + hd*64 + ct*16 + fr;
        st_sp<SPLIT>(yhi, ylo, off, v);
      }
  }
}

// ---------------- host side ----------------
struct Ptrs {
  float* x; float* cmb; float* part; float* cwl; int* tl; int* cnt;
  unsigned short *hhi,*hlo,*qhi,*qlo,*khi,*klo,*vthi,*vtlo,*yhi,*ylo,*Hhi,*Hlo;
  unsigned short *Wqkvh,*Wqkvl,*WOh,*WOl,*WGh,*WGl,*WUh,*WUl,*WDh,*WDl;
};

template<int S>
static void run_layer(const Ptrs& P, int l,
    const float* anw, const float* qw, const float* qb, const float* kvw, const float* kvb,
    const float* ow, const float* ob, const float* fnw, const float* rw,
    const float* gw, const float* uw, const float* dw,
    const float* nextw, unsigned short* nextdst, int writex, float scale, hipStream_t stream)
{
  (void)anw;
  k_wconv_qkvo<S><<<dim3(1024), dim3(256), 0, stream>>>(
      qw + (size_t)l*Dm*Dm, kvw + (size_t)l*Dm*2*Dm, ow + (size_t)l*Dm*Dm,
      P.Wqkvh, P.Wqkvl, P.WOh, P.WOl);
  k_mm<S,2><<<dim3(24,8,2), dim3(256), 0, stream>>>(P.hhi, P.hlo, P.Wqkvh, P.Wqkvl,
      P.part, Dm, Dm, 512, 3072);
  k_comb_qkvt<S><<<dim3(1280), dim3(256), 0, stream>>>(P.part, qb + l*Dm, kvb + l*2*Dm,
      P.qhi, P.qlo, P.khi, P.klo, P.vthi, P.vtlo);
  k_attn<S><<<dim3(64,16), dim3(256), 0, stream>>>(P.qhi,P.qlo,P.khi,P.klo,P.vthi,P.vtlo,P.yhi,P.ylo);
  k_mm<S,2><<<dim3(8,8,8), dim3(256), 0, stream>>>(P.yhi, P.ylo, P.WOh, P.WOl,
      P.part, Dm, Dm, 128, Dm);
  k_fuse_o<S><<<dim3(NT), dim3(256), 0, stream>>>(P.part, ob + l*Dm, fnw + l*Dm,
      rw + (size_t)l*Dm*4, P.x, P.hhi, P.hlo, P.cmb);
  k_wconv_gu<S><<<dim3(4097), dim3(256), 0, stream>>>(
      gw + (size_t)l*4*Dm*HIDm, uw + (size_t)l*4*Dm*HIDm, P.WGh, P.WGl, P.WUh, P.WUl,
      P.cmb, P.tl, P.cwl, P.cnt);
  k_guf<S><<<dim3(32,16,4), dim3(256), 0, stream>>>(P.hhi, P.hlo, P.WGh, P.WGl, P.WUh, P.WUl,
      P.tl, P.cwl, P.cnt, P.Hhi, P.Hlo, scale);
  k_wconv<S><<<dim3(16,32,4), dim3(256), 0, stream>>>(dw + (size_t)l*4*HIDm*Dm, P.WDh, P.WDl, HIDm, Dm);
  k_down<S><<<dim3(8,8,8), dim3(256), 0, stream>>>(P.Hhi, P.Hlo, P.WDh, P.WDl,
      P.tl, P.cnt, P.part);
  k_fuse_moe<<<dim3(NT), dim3(256), 0, stream>>>(P.part, P.cmb, nextw, P.x, nextdst, writex);
}

extern "C" void kernel_launch(void* const* d_in, const int* in_sizes, int n_in,
                              void* d_out, int out_size, void* d_ws, size_t ws_size,
                              hipStream_t stream)
{
  (void)in_sizes; (void)n_in; (void)out_size;
  const int*   idx = (const int*)d_in[0];
  const float* emb = (const float*)d_in[1];
  const float* anw = (const float*)d_in[2];
  const float* qw  = (const float*)d_in[3];
  const float* qb  = (const float*)d_in[4];
  const float* kvw = (const float*)d_in[5];
  const float* kvb = (const float*)d_in[6];
  const float* ow  = (const float*)d_in[7];
  const float* ob  = (const float*)d_in[8];
  const float* fnw = (const float*)d_in[9];
  const float* rw  = (const float*)d_in[10];
  const float* gw  = (const float*)d_in[11];
  const float* uw  = (const float*)d_in[12];
  const float* dw  = (const float*)d_in[13];
  const float* lnf = (const float*)d_in[14];

  constexpr size_t MB = (size_t)1<<20;
  constexpr size_t KB = (size_t)1<<10;
  char* sc = (char*)d_out;
  Ptrs P;
  P.x     = (float*)sc;                                   // [0,4)
  P.hhi   = (unsigned short*)(sc + 4*MB);
  P.hlo   = (unsigned short*)(sc + 6*MB);
  P.qhi   = (unsigned short*)(sc + 8*MB);
  P.qlo   = (unsigned short*)(sc + 10*MB);
  P.khi   = (unsigned short*)(sc + 12*MB);
  P.klo   = (unsigned short*)(sc + 14*MB);
  P.vthi  = (unsigned short*)(sc + 16*MB);
  P.vtlo  = (unsigned short*)(sc + 18*MB);
  P.yhi   = (unsigned short*)(sc + 20*MB);
  P.ylo   = (unsigned short*)(sc + 22*MB);
  P.cmb   = (float*)(sc + 24*MB);                         // 16KB
  P.tl    = (int*)(sc + 24*MB + 64*KB);
  P.cwl   = (float*)(sc + 24*MB + 128*KB);
  P.cnt   = (int*)(sc + 24*MB + 192*KB);
  P.Hhi   = (unsigned short*)(sc + 25*MB);                // [25,41)
  P.Hlo   = (unsigned short*)(sc + 41*MB);                // [41,57)
  P.Wqkvh = (unsigned short*)(sc + 57*MB);                // [57,63)
  P.Wqkvl = (unsigned short*)(sc + 63*MB);                // [63,69)
  P.WOh   = (unsigned short*)(sc + 69*MB);                // [69,71)
  P.WOl   = (unsigned short*)(sc + 71*MB);                // [71,73)
  P.WGh   = (unsigned short*)(sc + 57*MB);                // reuse after attn done
  P.WGl   = (unsigned short*)(sc + 73*MB);
  P.WUh   = (unsigned short*)(sc + 89*MB);                // [89,105)
  P.WUl   = (unsigned short*)(sc + 105*MB);               // [105,121)
  P.WDh   = (unsigned short*)(sc + 57*MB);                // reuse after guf done
  P.WDl   = (unsigned short*)(sc + 73*MB);
  P.part  = (float*)(sc + 89*MB);                         // up to 32MB [89,121)
  unsigned short* xhat  = (unsigned short*)d_ws;          // 2 MiB, survives logits
  unsigned short* emb16 = (unsigned short*)((char*)d_ws + 2*MB); // 62.5 MiB (if ws allows)
  const bool big_ws = ws_size >= 68*MB;
  float* out = (float*)d_out;

  const int gbase = big_ws ? 16000 : 0;
  k_init<3><<<dim3(gbase + NT), dim3(256), 0, stream>>>(idx, emb, P.x, emb16, gbase,
      anw, P.hhi, P.hlo);

  run_layer<3>(P, 0, anw, qw, qb, kvw, kvb, ow, ob, fnw, rw, gw, uw, dw,
               anw + Dm, P.hhi, 1, 1.0f, stream);
  run_layer<1>(P, 1, anw, qw, qb, kvw, kvb, ow, ob, fnw, rw, gw, uw, dw,
               lnf, xhat, 0, 0.70710678f, stream);

  if (big_ws)
    k_lg16<<<dim3(500), dim3(512), 0, stream>>>(xhat, emb16, out);
  else
    k_lg<<<dim3(2000), dim3(256), 0, stream>>>(xhat, emb, out);
}

// Round 17
// 721.139 us; speedup vs baseline: 1.0106x; 1.0106x over previous
//
#include <hip/hip_runtime.h>
#include <cmath>

typedef __attribute__((ext_vector_type(8))) _Float16 f16x8;
typedef __attribute__((ext_vector_type(8))) unsigned short u16x8;
typedef __attribute__((ext_vector_type(4))) float f32x4;

#define DEV static __device__ __forceinline__

constexpr int Dm   = 1024;
constexpr int HIDm = 2048;
constexpr int NT   = 1024;
constexpr int NV   = 32000;
constexpr float EPSf  = 1e-8f;
constexpr float LOSC  = 4096.0f;
constexpr float ILOSC = 1.0f / 4096.0f;

DEV unsigned short h2u(_Float16 h){ union{_Float16 h; unsigned short u;} v; v.h=h; return v.u; }

DEV f32x4 MF(f16x8 a, f16x8 b, f32x4 c){ return __builtin_amdgcn_mfma_f32_16x16x32_f16(a,b,c,0,0,0); }

typedef __attribute__((address_space(1))) void GV;
typedef __attribute__((address_space(3))) void LV;
DEV void gll16(const void* g, void* l){
  __builtin_amdgcn_global_load_lds((GV*)(__UINTPTR_TYPE__)g, (LV*)l, 16, 0, 0);
}

// BK=32 LDS swizzle (verified conflict-free R8): unit ^= (row>>1)&3
DEV int swk(int lane){ return (((lane&3) ^ ((lane>>3)&3))*8); }
DEV int rdc(int fr, int fg){ return ((fg ^ ((fr>>1)&3))*8); }

template<int SPLIT>
DEV void st_sp(unsigned short* __restrict__ hi, unsigned short* __restrict__ lo, size_t o, float v){
  _Float16 hh = (_Float16)v;
  hi[o] = h2u(hh);
  if constexpr (SPLIT==3) lo[o] = h2u((_Float16)((v - (float)hh)*LOSC));
}

// merged: emb f32->f16 pre-convert (bid<gbase) + token gather + first rms (bid>=gbase)
template<int SPLIT>
__global__ __launch_bounds__(256) void k_init(
    const int* __restrict__ idx, const float* __restrict__ emb,
    float* __restrict__ x, unsigned short* __restrict__ emb16, int gbase,
    const float* __restrict__ anw, unsigned short* __restrict__ hhi,
    unsigned short* __restrict__ hlo)
{
  const int b = blockIdx.x;
  if (b < gbase){
    const size_t i = ((size_t)b*256 + threadIdx.x)*8;
    const float4 v0 = *(const float4*)&emb[i];
    const float4 v1 = *(const float4*)&emb[i+4];
    u16x8 h;
    h[0]=h2u((_Float16)v0.x); h[1]=h2u((_Float16)v0.y);
    h[2]=h2u((_Float16)v0.z); h[3]=h2u((_Float16)v0.w);
    h[4]=h2u((_Float16)v1.x); h[5]=h2u((_Float16)v1.y);
    h[6]=h2u((_Float16)v1.z); h[7]=h2u((_Float16)v1.w);
    *(u16x8*)&emb16[i] = h;
    return;
  }
  const int t = b - gbase, tid = threadIdx.x, wv = tid>>6, lane = tid&63;
  const int c = tid*4;
  const float4 v = *(const float4*)&emb[(size_t)idx[t]*Dm + c];
  *(float4*)&x[(size_t)t*Dm + c] = v;
  float ss = v.x*v.x + v.y*v.y + v.z*v.z + v.w*v.w;
  #pragma unroll
  for (int d=1; d<64; d<<=1) ss += __shfl_xor(ss, d);
  __shared__ float red[4];
  if (lane==0) red[wv] = ss;
  __syncthreads();
  const float rstd = rsqrtf((red[0]+red[1]+red[2]+red[3])*(1.0f/Dm) + EPSf);
  const float4 w4 = *(const float4*)&anw[c];
  const float sv[4] = {v.x,v.y,v.z,v.w};
  const float wv4[4] = {w4.x,w4.y,w4.z,w4.w};
  #pragma unroll
  for (int j=0;j<4;++j)
    st_sp<SPLIT>(hhi, hlo, (size_t)t*Dm + c + j, sv[j]*rstd*wv4[j]);
}

// fused: x += sum(part z=0..7) + ob ; write x ; rms(fnw)->h planes ; router top2 -> cmb
template<int SPLIT>
__global__ __launch_bounds__(256) void k_fuse_o(
    const float* __restrict__ part, const float* __restrict__ ob,
    const float* __restrict__ fnw, const float* __restrict__ rw,
    float* __restrict__ x, unsigned short* __restrict__ hhi,
    unsigned short* __restrict__ hlo, float* __restrict__ cmb)
{
  const int t = blockIdx.x, tid = threadIdx.x, wv = tid>>6, lane = tid&63;
  const int c = tid*4;
  float4 s = *(float4*)&x[(size_t)t*Dm + c];
  #pragma unroll
  for (int z=0; z<8; ++z){
    const float4 p = *(const float4*)&part[((size_t)z*NT + t)*Dm + c];
    s.x+=p.x; s.y+=p.y; s.z+=p.z; s.w+=p.w;
  }
  const float4 b4 = *(const float4*)&ob[c];
  s.x+=b4.x; s.y+=b4.y; s.z+=b4.z; s.w+=b4.w;
  *(float4*)&x[(size_t)t*Dm + c] = s;

  float ss = s.x*s.x + s.y*s.y + s.z*s.z + s.w*s.w;
  #pragma unroll
  for (int d=1; d<64; d<<=1) ss += __shfl_xor(ss, d);
  __shared__ float red[4];
  if (lane==0) red[wv] = ss;
  __syncthreads();
  const float rstd = rsqrtf((red[0]+red[1]+red[2]+red[3])*(1.0f/Dm) + EPSf);

  const float4 w4 = *(const float4*)&fnw[c];
  const float sv[4] = {s.x,s.y,s.z,s.w};
  const float wv4[4] = {w4.x,w4.y,w4.z,w4.w};
  float hm[4];
  float lg[4] = {0.f,0.f,0.f,0.f};
  #pragma unroll
  for (int j=0;j<4;++j){
    hm[j] = sv[j]*rstd*wv4[j];
    st_sp<SPLIT>(hhi, hlo, (size_t)t*Dm + c + j, hm[j]);
    const float4 r4 = *(const float4*)&rw[(size_t)(c+j)*4];
    lg[0] += hm[j]*r4.x; lg[1] += hm[j]*r4.y; lg[2] += hm[j]*r4.z; lg[3] += hm[j]*r4.w;
  }
  #pragma unroll
  for (int d=1; d<64; d<<=1){
    lg[0]+=__shfl_xor(lg[0],d); lg[1]+=__shfl_xor(lg[1],d);
    lg[2]+=__shfl_xor(lg[2],d); lg[3]+=__shfl_xor(lg[3],d);
  }
  __shared__ float red2[4][4];
  if (lane==0){ red2[wv][0]=lg[0]; red2[wv][1]=lg[1]; red2[wv][2]=lg[2]; red2[wv][3]=lg[3]; }
  __syncthreads();
  if (tid==0){
    float L[4];
    #pragma unroll
    for (int e=0;e<4;++e) L[e] = red2[0][e]+red2[1][e]+red2[2][e]+red2[3][e];
    int s0 = 0;
    for (int e=1;e<4;++e) if (L[e] > L[s0]) s0 = e;
    int s1 = -1;
    for (int e=0;e<4;++e){ if (e==s0) continue; if (s1<0 || L[e] > L[s1]) s1 = e; }
    const float eb2 = expf(L[s1] - L[s0]);
    const float inv = 1.0f/(1.0f + eb2);
    float o[4] = {0.f,0.f,0.f,0.f};
    o[s0] = inv; o[s1] = eb2*inv;
    cmb[t*4+0]=o[0]; cmb[t*4+1]=o[1]; cmb[t*4+2]=o[2]; cmb[t*4+3]=o[3];
  }
}

// fused: x += moe(part, cmb) ; optional x write ; rms(w)->SPLIT1 planes
__global__ __launch_bounds__(256) void k_fuse_moe(
    const float* __restrict__ part, const float* __restrict__ cmb,
    const float* __restrict__ w, float* __restrict__ x,
    unsigned short* __restrict__ dst, int writex)
{
  const int t = blockIdx.x, tid = threadIdx.x, wv = tid>>6, lane = tid&63;
  const int c = tid*4;
  float4 s = *(float4*)&x[(size_t)t*Dm + c];
  #pragma unroll
  for (int e=0; e<4; ++e){
    if (cmb[(size_t)t*4 + e] > 0.f){
      const float4 p0 = *(const float4*)&part[((size_t)(e*2+0)*NT + t)*Dm + c];
      const float4 p1 = *(const float4*)&part[((size_t)(e*2+1)*NT + t)*Dm + c];
      s.x+=p0.x+p1.x; s.y+=p0.y+p1.y; s.z+=p0.z+p1.z; s.w+=p0.w+p1.w;
    }
  }
  if (writex) *(float4*)&x[(size_t)t*Dm + c] = s;
  float ss = s.x*s.x + s.y*s.y + s.z*s.z + s.w*s.w;
  #pragma unroll
  for (int d=1; d<64; d<<=1) ss += __shfl_xor(ss, d);
  __shared__ float red[4];
  if (lane==0) red[wv] = ss;
  __syncthreads();
  const float rstd = rsqrtf((red[0]+red[1]+red[2]+red[3])*(1.0f/Dm) + EPSf);
  const float4 w4 = *(const float4*)&w[c];
  const float sv[4] = {s.x,s.y,s.z,s.w};
  const float wv4[4] = {w4.x,w4.y,w4.z,w4.w};
  #pragma unroll
  for (int j=0;j<4;++j)
    dst[(size_t)t*Dm + c + j] = h2u((_Float16)(sv[j]*rstd*wv4[j]));
}

// transpose+split tile converter (64x64)
template<int SPLIT>
DEV void wconv_tile(const float* __restrict__ W, unsigned short* __restrict__ Whi,
                    unsigned short* __restrict__ Wlo, int K, int N, int n0, int k0,
                    float (*tile)[65], int t)
{
  const int r = t>>2;
  #pragma unroll
  for (int i=0;i<4;++i){
    const int c = (t&3)*16 + i*4;
    *(float4*)&tile[r][c] = *(const float4*)&W[(size_t)(k0+r)*N + n0 + c];
  }
  __syncthreads();
  const int n = t>>2;
  #pragma unroll
  for (int i=0;i<2;++i){
    const int kc = (t&3)*8 + i*32;
    u16x8 hi, lo;
    #pragma unroll
    for (int j=0;j<8;++j){
      const float v = tile[kc+j][n];
      const _Float16 hh = (_Float16)v;
      hi[j] = h2u(hh);
      if constexpr (SPLIT==3) lo[j] = h2u((_Float16)((v-(float)hh)*LOSC));
      else lo[j] = 0;
    }
    *(u16x8*)&Whi[(size_t)(n0+n)*K + k0 + kc] = hi;
    if constexpr (SPLIT==3) *(u16x8*)&Wlo[(size_t)(n0+n)*K + k0 + kc] = lo;
  }
}

template<int SPLIT>
__global__ __launch_bounds__(256) void k_wconv(
    const float* __restrict__ W, unsigned short* __restrict__ Whi,
    unsigned short* __restrict__ Wlo, int K, int N)
{
  __shared__ float tile[64][65];
  const size_t eb = (size_t)blockIdx.z * (size_t)K * N;
  wconv_tile<SPLIT>(W + eb, Whi + eb, Wlo + eb, K, N, blockIdx.x*64, blockIdx.y*64,
                    tile, threadIdx.x);
}

template<int SPLIT>
__global__ __launch_bounds__(256) void k_wconv_qkvo(
    const float* __restrict__ qw, const float* __restrict__ kvw, const float* __restrict__ ow,
    unsigned short* __restrict__ Wh, unsigned short* __restrict__ Wl,
    unsigned short* __restrict__ WOh, unsigned short* __restrict__ WOl)
{
  __shared__ float tile[64][65];
  const int b = blockIdx.x, t = threadIdx.x;
  if (b < 256){
    wconv_tile<SPLIT>(qw, Wh, Wl, Dm, Dm, (b&15)*64, (b>>4)*64, tile, t);
  } else if (b < 768){
    const int c = b - 256;
    wconv_tile<SPLIT>(kvw, Wh + (size_t)Dm*Dm, Wl + (size_t)Dm*Dm,
                      Dm, 2*Dm, (c&31)*64, (c>>5)*64, tile, t);
  } else {
    const int c = b - 768;
    wconv_tile<SPLIT>(ow, WOh, WOl, Dm, Dm, (c&15)*64, (c>>4)*64, tile, t);
  }
}

// merged gate+up weight conversion + expert scan (block 4096)
template<int SPLIT>
__global__ __launch_bounds__(256) void k_wconv_gu(
    const float* __restrict__ gw, const float* __restrict__ uw,
    unsigned short* __restrict__ WGh, unsigned short* __restrict__ WGl,
    unsigned short* __restrict__ WUh, unsigned short* __restrict__ WUl,
    const float* __restrict__ cmb, int* __restrict__ tl,
    float* __restrict__ cwl, int* __restrict__ cnt)
{
  __shared__ float tile[64][65];
  const int b = blockIdx.x, t = threadIdx.x;
  if (b >= 4096){
    const int e = t>>6, lane = t&63;
    int base = 0;
    for (int t0=0; t0<NT; t0+=64){
      const float w = cmb[(size_t)(t0+lane)*4 + e];
      const unsigned long long m = __ballot(w > 0.f);
      const int pre = __popcll(m & ((1ull<<lane)-1ull));
      if (w > 0.f){ tl[e*NT + base + pre] = t0+lane; cwl[e*NT + base + pre] = w; }
      base += __popcll(m);
    }
    if (lane==0) cnt[e] = base;
    return;
  }
  const int half = b >> 11;
  const int c = b & 2047;
  const int e = c >> 9, cc = c & 511;
  const size_t eb = (size_t)e * (size_t)Dm * HIDm;
  const int n0 = (cc&31)*64, k0 = (cc>>5)*64;
  if (half == 0)
    wconv_tile<SPLIT>(gw + eb, WGh + eb, WGl + eb, Dm, HIDm, n0, k0, tile, t);
  else
    wconv_tile<SPLIT>(uw + eb, WUh + eb, WUl + eb, Dm, HIDm, n0, k0, tile, t);
}

// 128x128-tile GEMM, f32 partial-store epilogue. ZMODE: 2 = K-chunk (koff=zz*K)
template<int SPLIT, int ZMODE>
__global__ __launch_bounds__(256) void k_mm(
    const unsigned short* __restrict__ Ahi, const unsigned short* __restrict__ Alo,
    const unsigned short* __restrict__ Bhi, const unsigned short* __restrict__ Blo,
    float* __restrict__ part, int lda, int ldb, int K, int ldo)
{
  constexpr int PL = (SPLIT==3)?2:1;
  __shared__ __align__(16) unsigned short As[PL][128][32];
  __shared__ __align__(16) unsigned short Bs[PL][128][32];
  const int tid=threadIdx.x, wv=tid>>6, lane=tid&63, fr=lane&15, fg=lane>>4;
  const int n0=blockIdx.x*128, r0=blockIdx.y*128, zz=blockIdx.z;
  const int wr=(wv>>1)*64, wc=(wv&1)*64;
  const int sr=lane>>2, sk=swk(lane);
  const int rc = rdc(fr, fg);

  const f32x4 z4={0.f,0.f,0.f,0.f};
  f32x4 accM[4][4], accC[4][4];
  #pragma unroll
  for (int i=0;i<4;++i)
    #pragma unroll
    for (int j=0;j<4;++j){ accM[i][j]=z4; accC[i][j]=z4; }

  for (int kt=0; kt<K; kt+=32){
    #pragma unroll
    for (int i=0;i<2;++i){
      const int rr = wv*32 + i*16 + sr;
      size_t ao, bo;
      if constexpr (ZMODE==2){
        ao = (size_t)(r0+rr)*lda + zz*K + kt + sk;
        bo = (size_t)(n0+rr)*ldb + zz*K + kt + sk;
      } else {
        ao = (size_t)(r0+rr)*lda + kt + sk;
        bo = (size_t)(n0+rr)*ldb + kt + sk;
      }
      gll16(&Ahi[ao], &As[0][wv*32+i*16][0]);
      if constexpr (SPLIT==3) gll16(&Alo[ao], &As[1][wv*32+i*16][0]);
      gll16(&Bhi[bo], &Bs[0][wv*32+i*16][0]);
      if constexpr (SPLIT==3) gll16(&Blo[bo], &Bs[1][wv*32+i*16][0]);
    }
    __syncthreads();
    f16x8 a[4][PL], b[4][PL];
    #pragma unroll
    for (int rt=0;rt<4;++rt)
      #pragma unroll
      for (int p=0;p<PL;++p) a[rt][p] = *(const f16x8*)&As[p][wr+rt*16+fr][rc];
    #pragma unroll
    for (int ct=0;ct<4;++ct)
      #pragma unroll
      for (int p=0;p<PL;++p) b[ct][p] = *(const f16x8*)&Bs[p][wc+ct*16+fr][rc];
    #pragma unroll
    for (int rt=0;rt<4;++rt)
      #pragma unroll
      for (int ct=0;ct<4;++ct){
        accM[rt][ct] = MF(a[rt][0], b[ct][0], accM[rt][ct]);
        if constexpr (SPLIT==3){
          accC[rt][ct] = MF(a[rt][0], b[ct][1], accC[rt][ct]);
          accC[rt][ct] = MF(a[rt][1], b[ct][0], accC[rt][ct]);
        }
      }
    __syncthreads();
  }

  #pragma unroll
  for (int rt=0;rt<4;++rt)
    #pragma unroll
    for (int ct=0;ct<4;++ct)
      #pragma unroll
      for (int j=0;j<4;++j){
        const int row = r0 + wr + rt*16 + fg*4 + j;
        const int col = n0 + wc + ct*16 + fr;
        float v = accM[rt][ct][j];
        if constexpr (SPLIT==3) v += accC[rt][ct][j]*ILOSC;
        part[((size_t)zz*NT + row)*ldo + col] = v;
      }
}

// merged qkv combine: bid<1024 -> q/k rows; else v transpose tiles
template<int SPLIT>
__global__ __launch_bounds__(256) void k_comb_qkvt(
    const float* __restrict__ part, const float* __restrict__ qb, const float* __restrict__ kvb,
    unsigned short* __restrict__ qhi, unsigned short* __restrict__ qlo,
    unsigned short* __restrict__ khi, unsigned short* __restrict__ klo,
    unsigned short* __restrict__ vthi, unsigned short* __restrict__ vtlo)
{
  __shared__ float tile[64][65];
  const int bid = blockIdx.x, tid = threadIdx.x;
  if (bid < 1024){
    const int t = bid;
    #pragma unroll
    for (int i=0;i<2;++i){
      const int col = tid*4 + i*1024;
      const float4 p0 = *(const float4*)&part[(size_t)t*3072 + col];
      const float4 p1 = *(const float4*)&part[((size_t)NT + t)*3072 + col];
      float v[4] = {p0.x+p1.x, p0.y+p1.y, p0.z+p1.z, p0.w+p1.w};
      #pragma unroll
      for (int j=0;j<4;++j){
        const int c = col + j;
        if (c < Dm) st_sp<SPLIT>(qhi, qlo, (size_t)t*Dm + c, v[j] + qb[c]);
        else        st_sp<SPLIT>(khi, klo, (size_t)t*Dm + (c-Dm), v[j] + kvb[c-Dm]);
      }
    }
  } else {
    const int c = bid - 1024;
    const int d0 = (c&15)*64, t0 = (c>>4)*64;
    {
      const int tl_ = tid>>2, dc = (tid&3)*16;
      #pragma unroll
      for (int i=0;i<4;++i){
        const int d = dc + i*4;
        const float4 p0 = *(const float4*)&part[(size_t)(t0+tl_)*3072 + 2048 + d0 + d];
        const float4 p1 = *(const float4*)&part[((size_t)NT + t0+tl_)*3072 + 2048 + d0 + d];
        tile[tl_][d+0] = p0.x+p1.x + kvb[1024+d0+d+0];
        tile[tl_][d+1] = p0.y+p1.y + kvb[1024+d0+d+1];
        tile[tl_][d+2] = p0.z+p1.z + kvb[1024+d0+d+2];
        tile[tl_][d+3] = p0.w+p1.w + kvb[1024+d0+d+3];
      }
    }
    __syncthreads();
    #pragma unroll
    for (int i=0;i<2;++i){
      const int u = tid + i*256;
      const int dl = u>>3, tch = (u&7)*8;
      u16x8 hi, lo;
      #pragma unroll
      for (int j=0;j<8;++j){
        const float v = tile[tch+j][dl];
        const _Float16 hh = (_Float16)v;
        hi[j] = h2u(hh);
        if constexpr (SPLIT==3) lo[j] = h2u((_Float16)((v-(float)hh)*LOSC));
        else lo[j] = 0;
      }
      *(u16x8*)&vthi[(size_t)(d0+dl)*NT + t0 + tch] = hi;
      if constexpr (SPLIT==3) *(u16x8*)&vtlo[(size_t)(d0+dl)*NT + t0 + tch] = lo;
    }
  }
}

// sparse down-proj, K split in 2: z = e*2+ks; scatter to part[e*2+ks][token]
template<int SPLIT>
__global__ __launch_bounds__(256) void k_down(
    const unsigned short* __restrict__ Ahi, const unsigned short* __restrict__ Alo,
    const unsigned short* __restrict__ Bhi, const unsigned short* __restrict__ Blo,
    const int* __restrict__ tl, const int* __restrict__ cnt,
    float* __restrict__ part)
{
  constexpr int PL = (SPLIT==3)?2:1;
  const int zz = blockIdx.z, e = zz>>1, ks = zz&1;
  const int r0 = blockIdx.y*128, n0 = blockIdx.x*128;
  const int cn = cnt[e];
  if (r0 >= cn) return;
  __shared__ __align__(16) unsigned short As[PL][128][32];
  __shared__ __align__(16) unsigned short Bs[PL][128][32];
  __shared__ int tl_s[128];
  const int tid=threadIdx.x, wv=tid>>6, lane=tid&63, fr=lane&15, fg=lane>>4;
  const int wr=(wv>>1)*64, wc=(wv&1)*64;
  const int sr=lane>>2, sk=swk(lane);
  const int rc = rdc(fr, fg);
  if (tid < 128) tl_s[tid] = (r0+tid < cn) ? tl[e*NT + r0 + tid] : -1;

  const f32x4 z4={0.f,0.f,0.f,0.f};
  f32x4 accM[4][4], accC[4][4];
  #pragma unroll
  for (int i=0;i<4;++i)
    #pragma unroll
    for (int j=0;j<4;++j){ accM[i][j]=z4; accC[i][j]=z4; }

  const int kbeg = ks*1024, kend = kbeg + 1024;
  for (int kt=kbeg; kt<kend; kt+=32){
    #pragma unroll
    for (int i=0;i<2;++i){
      const int rr = wv*32 + i*16 + sr;
      const size_t ao = (size_t)((e<<10) + r0 + rr)*HIDm + kt + sk;
      const size_t bo = (size_t)e*((size_t)Dm*HIDm) + (size_t)(n0+rr)*HIDm + kt + sk;
      gll16(&Ahi[ao], &As[0][wv*32+i*16][0]);
      if constexpr (SPLIT==3) gll16(&Alo[ao], &As[1][wv*32+i*16][0]);
      gll16(&Bhi[bo], &Bs[0][wv*32+i*16][0]);
      if constexpr (SPLIT==3) gll16(&Blo[bo], &Bs[1][wv*32+i*16][0]);
    }
    __syncthreads();
    f16x8 a[4][PL], b[4][PL];
    #pragma unroll
    for (int rt=0;rt<4;++rt)
      #pragma unroll
      for (int p=0;p<PL;++p) a[rt][p] = *(const f16x8*)&As[p][wr+rt*16+fr][rc];
    #pragma unroll
    for (int ct=0;ct<4;++ct)
      #pragma unroll
      for (int p=0;p<PL;++p) b[ct][p] = *(const f16x8*)&Bs[p][wc+ct*16+fr][rc];
    #pragma unroll
    for (int rt=0;rt<4;++rt)
      #pragma unroll
      for (int ct=0;ct<4;++ct){
        accM[rt][ct] = MF(a[rt][0], b[ct][0], accM[rt][ct]);
        if constexpr (SPLIT==3){
          accC[rt][ct] = MF(a[rt][0], b[ct][1], accC[rt][ct]);
          accC[rt][ct] = MF(a[rt][1], b[ct][0], accC[rt][ct]);
        }
      }
    __syncthreads();
  }

  #pragma unroll
  for (int rt=0;rt<4;++rt)
    #pragma unroll
    for (int ct=0;ct<4;++ct)
      #pragma unroll
      for (int j=0;j<4;++j){
        const int i = wr + rt*16 + fg*4 + j;
        const int col = n0 + wc + ct*16 + fr;
        float v = accM[rt][ct][j];
        if constexpr (SPLIT==3) v += accC[rt][ct][j]*ILOSC;
        const int tok = tl_s[i];
        if (tok >= 0) part[((size_t)zz*NT + tok)*Dm + col] = v;
      }
}

// sparse fused gate/up GEMM (8-wave, R15-proven): 512 threads, tile 128(M)x64(N)
template<int SPLIT>
__global__ __launch_bounds__(512) void k_guf(
    const unsigned short* __restrict__ Ahi, const unsigned short* __restrict__ Alo,
    const unsigned short* __restrict__ Ghi, const unsigned short* __restrict__ Glo,
    const unsigned short* __restrict__ Uhi, const unsigned short* __restrict__ Ulo,
    const int* __restrict__ tl, const float* __restrict__ cwl, const int* __restrict__ cnt,
    unsigned short* __restrict__ Hhi, unsigned short* __restrict__ Hlo, float scale)
{
  constexpr int PL=(SPLIT==3)?2:1;
  const int e = blockIdx.z, r0 = blockIdx.y*128, n0 = blockIdx.x*64;
  const int cn = cnt[e];
  if (r0 >= cn) return;
  __shared__ __align__(16) unsigned short As[PL][128][32];
  __shared__ __align__(16) unsigned short Gs[PL][64][32];
  __shared__ __align__(16) unsigned short Us[PL][64][32];
  __shared__ float cw_s[128];
  const int tid=threadIdx.x, wv=tid>>6, lane=tid&63, fr=lane&15, fg=lane>>4;
  const int wr=(wv>>1)*32, wc=(wv&1)*32;
  const int sr=lane>>2, sk=swk(lane);
  const int rc = rdc(fr, fg);
  const size_t ebW = (size_t)e * ((size_t)HIDm*Dm);
  if (tid < 128) cw_s[tid] = (r0+tid < cn) ? cwl[e*NT + r0 + tid]*scale : 0.f;

  const int lrA = r0 + wv*16 + sr;
  const int tokA = tl[e*NT + (lrA < cn ? lrA : cn-1)];
  const size_t abase = (size_t)tokA*Dm + sk;
  const int rrB = (wv&3)*16 + sr;
  const size_t bbase = ebW + (size_t)(n0+rrB)*Dm + sk;

  const f32x4 z4={0.f,0.f,0.f,0.f};
  f32x4 aGM[2][2],aGC[2][2],aUM[2][2],aUC[2][2];
  #pragma unroll
  for (int i=0;i<2;++i)
    #pragma unroll
    for (int j=0;j<2;++j){ aGM[i][j]=z4; aGC[i][j]=z4; aUM[i][j]=z4; aUC[i][j]=z4; }

  for (int kt=0; kt<Dm; kt+=32){
    gll16(&Ahi[abase + kt], &As[0][wv*16][0]);
    if constexpr (SPLIT==3) gll16(&Alo[abase + kt], &As[1][wv*16][0]);
    if (wv < 4){
      gll16(&Ghi[bbase + kt], &Gs[0][(wv&3)*16][0]);
      if constexpr (SPLIT==3) gll16(&Glo[bbase + kt], &Gs[1][(wv&3)*16][0]);
    } else {
      gll16(&Uhi[bbase + kt], &Us[0][(wv&3)*16][0]);
      if constexpr (SPLIT==3) gll16(&Ulo[bbase + kt], &Us[1][(wv&3)*16][0]);
    }
    __syncthreads();
    f16x8 a[2][PL], bg[2][PL], bu[2][PL];
    #pragma unroll
    for (int rt=0;rt<2;++rt)
      #pragma unroll
      for (int p=0;p<PL;++p) a[rt][p] = *(const f16x8*)&As[p][wr+rt*16+fr][rc];
    #pragma unroll
    for (int ct=0;ct<2;++ct)
      #pragma unroll
      for (int p=0;p<PL;++p){
        bg[ct][p] = *(const f16x8*)&Gs[p][wc+ct*16+fr][rc];
        bu[ct][p] = *(const f16x8*)&Us[p][wc+ct*16+fr][rc];
      }
    #pragma unroll
    for (int rt=0;rt<2;++rt)
      #pragma unroll
      for (int ct=0;ct<2;++ct){
        aGM[rt][ct] = MF(a[rt][0], bg[ct][0], aGM[rt][ct]);
        aUM[rt][ct] = MF(a[rt][0], bu[ct][0], aUM[rt][ct]);
        if constexpr (SPLIT==3){
          aGC[rt][ct] = MF(a[rt][0], bg[ct][1], aGC[rt][ct]);
          aGC[rt][ct] = MF(a[rt][1], bg[ct][0], aGC[rt][ct]);
          aUC[rt][ct] = MF(a[rt][0], bu[ct][1], aUC[rt][ct]);
          aUC[rt][ct] = MF(a[rt][1], bu[ct][0], aUC[rt][ct]);
        }
      }
    __syncthreads();
  }
  #pragma unroll
  for (int rt=0;rt<2;++rt)
    #pragma unroll
    for (int ct=0;ct<2;++ct)
      #pragma unroll
      for (int j=0;j<4;++j){
        const int i = wr + rt*16 + fg*4 + j;
        const int row = r0 + i;
        const int col = n0 + wc + ct*16 + fr;
        float g2 = aGM[rt][ct][j], u = aUM[rt][ct][j];
        if constexpr (SPLIT==3){ g2 += aGC[rt][ct][j]*ILOSC; u += aUC[rt][ct][j]*ILOSC; }
        const float cw = cw_s[i];
        const float h = (g2/(1.0f + expf(-g2))) * u * cw;
        st_sp<SPLIT>(Hhi, Hlo, (size_t)((e<<10) + row)*HIDm + col, h);
      }
}

// logits GEMM, fallback: in-kernel B convert, BK=32
__global__ __launch_bounds__(256) void k_lg(
    const unsigned short* __restrict__ Ahi, const float* __restrict__ emb,
    float* __restrict__ out)
{
  __shared__ __align__(16) unsigned short As[128][32];
  __shared__ __align__(16) unsigned short Bs[128][32];
  const int tid=threadIdx.x, wv=tid>>6, lane=tid&63, fr=lane&15, fg=lane>>4;
  const int w = (blockIdx.x & 7)*250 + (blockIdx.x >> 3);
  const int n0 = (w>>3)*128, r0 = (w&7)*128;
  const int wr=(wv>>1)*64, wc=(wv&1)*64;
  const int sr=lane>>2, sk=swk(lane);
  const int rc = rdc(fr, fg);
  const int br = tid>>1;
  const f32x4 z4={0.f,0.f,0.f,0.f};
  f32x4 acc[4][4];
  #pragma unroll
  for (int i=0;i<4;++i)
    #pragma unroll
    for (int j=0;j<4;++j) acc[i][j]=z4;

  for (int kt=0; kt<Dm; kt+=32){
    #pragma unroll
    for (int i=0;i<2;++i){
      const int rr = wv*32 + i*16 + sr;
      gll16(&Ahi[(size_t)(r0+rr)*Dm + kt + sk], &As[wv*32+i*16][0]);
    }
    {
      const int bc = (tid&1)*16;
      const float* s = &emb[(size_t)(n0+br)*Dm + kt + bc];
      const float4 v0 = *(const float4*)s;
      const float4 v1 = *(const float4*)(s+4);
      const float4 v2 = *(const float4*)(s+8);
      const float4 v3 = *(const float4*)(s+12);
      u16x8 h0, h1;
      h0[0]=h2u((_Float16)v0.x); h0[1]=h2u((_Float16)v0.y);
      h0[2]=h2u((_Float16)v0.z); h0[3]=h2u((_Float16)v0.w);
      h0[4]=h2u((_Float16)v1.x); h0[5]=h2u((_Float16)v1.y);
      h0[6]=h2u((_Float16)v1.z); h0[7]=h2u((_Float16)v1.w);
      h1[0]=h2u((_Float16)v2.x); h1[1]=h2u((_Float16)v2.y);
      h1[2]=h2u((_Float16)v2.z); h1[3]=h2u((_Float16)v2.w);
      h1[4]=h2u((_Float16)v3.x); h1[5]=h2u((_Float16)v3.y);
      h1[6]=h2u((_Float16)v3.z); h1[7]=h2u((_Float16)v3.w);
      const int s_ = (br>>1)&3;
      const int u0 = (tid&1)*2;
      *(u16x8*)&Bs[br][(u0^s_)*8]     = h0;
      *(u16x8*)&Bs[br][((u0+1)^s_)*8] = h1;
    }
    __syncthreads();
    f16x8 a[4], b[4];
    #pragma unroll
    for (int rt=0;rt<4;++rt) a[rt] = *(const f16x8*)&As[wr+rt*16+fr][rc];
    #pragma unroll
    for (int ct=0;ct<4;++ct) b[ct] = *(const f16x8*)&Bs[wc+ct*16+fr][rc];
    #pragma unroll
    for (int rt=0;rt<4;++rt)
      #pragma unroll
      for (int ct=0;ct<4;++ct) acc[rt][ct] = MF(a[rt], b[ct], acc[rt][ct]);
    __syncthreads();
  }
  #pragma unroll
  for (int rt=0;rt<4;++rt)
    #pragma unroll
    for (int ct=0;ct<4;++ct)
      #pragma unroll
      for (int j=0;j<4;++j)
        out[(size_t)(r0+wr+rt*16+fg*4+j)*NV + n0+wc+ct*16+fr] = acc[rt][ct][j];
}

// logits GEMM fast path (R11-proven): 256x256 tile, 512 threads (8 waves 2Mx4N),
// BK=64, row&7-XOR unit swizzle, bijective XCD swizzle for 500 blocks
__global__ __launch_bounds__(512) void k_lg16(
    const unsigned short* __restrict__ Ahi, const unsigned short* __restrict__ B16,
    float* __restrict__ out)
{
  __shared__ __align__(16) unsigned short As[256][64];
  __shared__ __align__(16) unsigned short Bs[256][64];
  const int tid=threadIdx.x, wv=tid>>6, lane=tid&63, fr=lane&15, fg=lane>>4;
  const int xcd = blockIdx.x & 7, ii = blockIdx.x >> 3;
  const int w = (xcd < 4 ? xcd*63 : 252 + (xcd-4)*62) + ii;   // bijective, 500=4*63+4*62
  const int n0 = (w>>2)*256, r0 = (w&3)*256;
  const int wrow=(wv>>2)*128, wcol=(wv&3)*64;
  const int srow = lane>>3;
  const int sk = (((lane&7) ^ srow)*8);
  const f32x4 z4={0.f,0.f,0.f,0.f};
  f32x4 acc[8][4];
  #pragma unroll
  for (int i=0;i<8;++i)
    #pragma unroll
    for (int j=0;j<4;++j) acc[i][j]=z4;

  for (int kt=0; kt<Dm; kt+=64){
    #pragma unroll
    for (int i=0;i<4;++i){
      const int rr = wv*32 + i*8 + srow;
      gll16(&Ahi[(size_t)(r0+rr)*Dm + kt + sk], &As[wv*32+i*8][0]);
      gll16(&B16[(size_t)(n0+rr)*Dm + kt + sk], &Bs[wv*32+i*8][0]);
    }
    __syncthreads();
    #pragma unroll
    for (int kk=0;kk<2;++kk){
      f16x8 a[8], b[4];
      #pragma unroll
      for (int rt=0;rt<8;++rt)
        a[rt] = *(const f16x8*)&As[wrow+rt*16+fr][(((kk*4+fg) ^ (fr&7))*8)];
      #pragma unroll
      for (int ct=0;ct<4;++ct)
        b[ct] = *(const f16x8*)&Bs[wcol+ct*16+fr][(((kk*4+fg) ^ (fr&7))*8)];
      #pragma unroll
      for (int rt=0;rt<8;++rt)
        #pragma unroll
        for (int ct=0;ct<4;++ct) acc[rt][ct] = MF(a[rt], b[ct], acc[rt][ct]);
    }
    __syncthreads();
  }
  #pragma unroll
  for (int rt=0;rt<8;++rt)
    #pragma unroll
    for (int ct=0;ct<4;++ct)
      #pragma unroll
      for (int j=0;j<4;++j)
        out[(size_t)(r0+wrow+rt*16+fg*4+j)*NV + n0+wcol+ct*16+fr] = acc[rt][ct][j];
}

// flash-style attention v3: 4-wave blocks, intra-block flash split-K
// (wave w handles k-tiles kt%4==w; LSE merge tree), longest-first dispatch.
template<int SPLIT>
__global__ __launch_bounds__(256) void k_attn(
    const unsigned short* __restrict__ qhi, const unsigned short* __restrict__ qlo,
    const unsigned short* __restrict__ khi, const unsigned short* __restrict__ klo,
    const unsigned short* __restrict__ vthi, const unsigned short* __restrict__ vtlo,
    unsigned short* __restrict__ yhi, unsigned short* __restrict__ ylo)
{
  constexpr int PL = (SPLIT==3) ? 2 : 1;
  const int qt = (int)gridDim.x - 1 - (int)blockIdx.x;   // longest blocks first
  const int hd = blockIdx.y;
  const int tid = threadIdx.x, wv = tid>>6, lane = tid&63;
  const int fr = lane&15, fg = lane>>4;
  const int rbase = qt*16;
  const float slope = (float)(hd+1) * (1.0f/16.0f);

  __shared__ __align__(16) unsigned short Ps[4][PL][16][32];
  __shared__ float Lm[3][64][4], Ll[3][64][4];
  __shared__ float LyM[3][64][16];
  __shared__ float LyC[(SPLIT==3)?3:1][64][16];

  f16x8 aq[2][PL];
  #pragma unroll
  for (int c=0;c<2;++c){
    const size_t off = (size_t)(rbase+fr)*Dm + hd*64 + c*32 + fg*8;
    aq[c][0] = *(const f16x8*)&qhi[off];
    if constexpr (SPLIT==3) aq[c][1] = *(const f16x8*)&qlo[off];
  }

  const f32x4 z4 = {0.f,0.f,0.f,0.f};
  f32x4 yM[4], yC[4];
  #pragma unroll
  for (int ct=0;ct<4;++ct){ yM[ct]=z4; yC[ct]=z4; }
  float m[4], lsum[4];
  #pragma unroll
  for (int j=0;j<4;++j){ m[j] = -INFINITY; lsum[j] = 0.f; }

  const int nkt = qt/2 + 1;
  for (int kt=wv; kt<nkt; kt+=4){
    f32x4 sM[2], sC[2];
    sM[0]=z4; sM[1]=z4; sC[0]=z4; sC[1]=z4;
    #pragma unroll
    for (int kh=0; kh<2; ++kh){
      #pragma unroll
      for (int c=0;c<2;++c){
        const size_t off = (size_t)(kt*32 + kh*16 + fr)*Dm + hd*64 + c*32 + fg*8;
        const f16x8 b0 = *(const f16x8*)&khi[off];
        sM[kh] = MF(aq[c][0], b0, sM[kh]);
        if constexpr (SPLIT==3){
          const f16x8 b1 = *(const f16x8*)&klo[off];
          sC[kh] = MF(aq[c][0], b1, sC[kh]);
          sC[kh] = MF(aq[c][1], b0, sC[kh]);
        }
      }
    }
    float sv[2][4], mx[4];
    #pragma unroll
    for (int j=0;j<4;++j) mx[j] = -INFINITY;
    #pragma unroll
    for (int kh=0; kh<2; ++kh)
      #pragma unroll
      for (int j=0;j<4;++j){
        const int kcol = kt*32 + kh*16 + fr;
        const int row  = rbase + fg*4 + j;
        float s = sM[kh][j];
        if constexpr (SPLIT==3) s += sC[kh][j]*ILOSC;
        s = s*0.125f + slope*(float)(kcol - row);
        sv[kh][j] = (kcol > row) ? -INFINITY : s;
        mx[j] = fmaxf(mx[j], sv[kh][j]);
      }
    #pragma unroll
    for (int d=1; d<16; d<<=1)
      #pragma unroll
      for (int j=0;j<4;++j) mx[j] = fmaxf(mx[j], __shfl_xor(mx[j], d));
    float resc[4];
    #pragma unroll
    for (int j=0;j<4;++j){
      const float mn = fmaxf(m[j], mx[j]);
      resc[j] = expf(m[j] - mn);
      m[j] = mn;
    }
    float p[2][4], psum[4];
    #pragma unroll
    for (int j=0;j<4;++j) psum[j] = 0.f;
    #pragma unroll
    for (int kh=0;kh<2;++kh)
      #pragma unroll
      for (int j=0;j<4;++j){
        const float pv = (sv[kh][j] == -INFINITY) ? 0.f : expf(sv[kh][j] - m[j]);
        p[kh][j] = pv; psum[j] += pv;
      }
    #pragma unroll
    for (int d=1; d<16; d<<=1)
      #pragma unroll
      for (int j=0;j<4;++j) psum[j] += __shfl_xor(psum[j], d);
    #pragma unroll
    for (int j=0;j<4;++j) lsum[j] = lsum[j]*resc[j] + psum[j];
    #pragma unroll
    for (int ct=0;ct<4;++ct)
      #pragma unroll
      for (int j=0;j<4;++j){ yM[ct][j]*=resc[j]; yC[ct][j]*=resc[j]; }
    #pragma unroll
    for (int kh=0;kh<2;++kh)
      #pragma unroll
      for (int j=0;j<4;++j){
        const float pv = p[kh][j];
        _Float16 ph = (_Float16)pv;
        Ps[wv][0][fg*4+j][kh*16+fr] = h2u(ph);
        if constexpr (SPLIT==3)
          Ps[wv][1][fg*4+j][kh*16+fr] = h2u((_Float16)((pv-(float)ph)*LOSC));
      }
    asm volatile("s_waitcnt lgkmcnt(0)" ::: "memory");
    f16x8 pa[PL];
    pa[0] = *(const f16x8*)&Ps[wv][0][fr][fg*8];
    if constexpr (SPLIT==3) pa[1] = *(const f16x8*)&Ps[wv][1][fr][fg*8];
    #pragma unroll
    for (int ct=0;ct<4;++ct){
      const size_t off = (size_t)(hd*64 + ct*16 + fr)*NT + kt*32 + fg*8;
      const f16x8 v0 = *(const f16x8*)&vthi[off];
      yM[ct] = MF(pa[0], v0, yM[ct]);
      if constexpr (SPLIT==3){
        const f16x8 v1 = *(const f16x8*)&vtlo[off];
        yC[ct] = MF(pa[0], v1, yC[ct]);
        yC[ct] = MF(pa[1], v0, yC[ct]);
      }
    }
    asm volatile("s_waitcnt lgkmcnt(0)" ::: "memory");
  }

  // LSE merge: waves 1..3 publish state, wave0 folds them in and stores.
  if (wv > 0){
    const int s = wv - 1;
    #pragma unroll
    for (int j=0;j<4;++j){ Lm[s][lane][j] = m[j]; Ll[s][lane][j] = lsum[j]; }
    #pragma unroll
    for (int ct=0;ct<4;++ct)
      #pragma unroll
      for (int j=0;j<4;++j){
        LyM[s][lane][ct*4+j] = yM[ct][j];
        if constexpr (SPLIT==3) LyC[s][lane][ct*4+j] = yC[ct][j];
      }
  }
  __syncthreads();
  if (wv == 0){
    #pragma unroll
    for (int s=0; s<3; ++s){
      #pragma unroll
      for (int j=0;j<4;++j){
        const float m1 = Lm[s][lane][j];
        const float M  = fmaxf(m[j], m1);
        const float a0 = expf(m[j] - M);   // m[j] finite (tile 0 is wave0's)
        const float a1 = expf(m1 - M);     // exp(-inf)=0 when wave s+1 idle
        lsum[j] = lsum[j]*a0 + Ll[s][lane][j]*a1;
        #pragma unroll
        for (int ct=0;ct<4;++ct){
          yM[ct][j] = yM[ct][j]*a0 + LyM[s][lane][ct*4+j]*a1;
          if constexpr (SPLIT==3) yC[ct][j] = yC[ct][j]*a0 + LyC[s][lane][ct*4+j]*a1;
        }
        m[j] = M;
      }
    }
    #pragma unroll
    for (int ct=0;ct<4;++ct)
      #pragma unroll
      for (int j=0;j<4;++j){
        float v = yM[ct][j];
        if constexpr (SPLIT==3) v += yC[ct][j]*ILOSC;
        v /= lsum[j];
        const size_t off = (size_t)(rbase + fg*4 + j)*Dm + hd*64 + ct*16 + fr;
        st_sp<SPLIT>(yhi, ylo, off, v);
      }
  }
}

// ---------------- host side ----------------
struct Ptrs {
  float* x; float* cmb; float* part; float* cwl; int* tl; int* cnt;
  unsigned short *hhi,*hlo,*qhi,*qlo,*khi,*klo,*vthi,*vtlo,*yhi,*ylo,*Hhi,*Hlo;
  unsigned short *Wqkvh,*Wqkvl,*WOh,*WOl,*WGh,*WGl,*WUh,*WUl,*WDh,*WDl;
};

template<int S>
static void run_layer(const Ptrs& P, int l,
    const float* anw, const float* qw, const float* qb, const float* kvw, const float* kvb,
    const float* ow, const float* ob, const float* fnw, const float* rw,
    const float* gw, const float* uw, const float* dw,
    const float* nextw, unsigned short* nextdst, int writex, float scale, hipStream_t stream)
{
  (void)anw;
  k_wconv_qkvo<S><<<dim3(1024), dim3(256), 0, stream>>>(
      qw + (size_t)l*Dm*Dm, kvw + (size_t)l*Dm*2*Dm, ow + (size_t)l*Dm*Dm,
      P.Wqkvh, P.Wqkvl, P.WOh, P.WOl);
  k_mm<S,2><<<dim3(24,8,2), dim3(256), 0, stream>>>(P.hhi, P.hlo, P.Wqkvh, P.Wqkvl,
      P.part, Dm, Dm, 512, 3072);
  k_comb_qkvt<S><<<dim3(1280), dim3(256), 0, stream>>>(P.part, qb + l*Dm, kvb + l*2*Dm,
      P.qhi, P.qlo, P.khi, P.klo, P.vthi, P.vtlo);
  k_attn<S><<<dim3(64,16), dim3(256), 0, stream>>>(P.qhi,P.qlo,P.khi,P.klo,P.vthi,P.vtlo,P.yhi,P.ylo);
  k_mm<S,2><<<dim3(8,8,8), dim3(256), 0, stream>>>(P.yhi, P.ylo, P.WOh, P.WOl,
      P.part, Dm, Dm, 128, Dm);
  k_fuse_o<S><<<dim3(NT), dim3(256), 0, stream>>>(P.part, ob + l*Dm, fnw + l*Dm,
      rw + (size_t)l*Dm*4, P.x, P.hhi, P.hlo, P.cmb);
  k_wconv_gu<S><<<dim3(4097), dim3(256), 0, stream>>>(
      gw + (size_t)l*4*Dm*HIDm, uw + (size_t)l*4*Dm*HIDm, P.WGh, P.WGl, P.WUh, P.WUl,
      P.cmb, P.tl, P.cwl, P.cnt);
  k_guf<S><<<dim3(32,8,4), dim3(512), 0, stream>>>(P.hhi, P.hlo, P.WGh, P.WGl, P.WUh, P.WUl,
      P.tl, P.cwl, P.cnt, P.Hhi, P.Hlo, scale);
  k_wconv<S><<<dim3(16,32,4), dim3(256), 0, stream>>>(dw + (size_t)l*4*HIDm*Dm, P.WDh, P.WDl, HIDm, Dm);
  k_down<S><<<dim3(8,8,8), dim3(256), 0, stream>>>(P.Hhi, P.Hlo, P.WDh, P.WDl,
      P.tl, P.cnt, P.part);
  k_fuse_moe<<<dim3(NT), dim3(256), 0, stream>>>(P.part, P.cmb, nextw, P.x, nextdst, writex);
}

extern "C" void kernel_launch(void* const* d_in, const int* in_sizes, int n_in,
                              void* d_out, int out_size, void* d_ws, size_t ws_size,
                              hipStream_t stream)
{
  (void)in_sizes; (void)n_in; (void)out_size;
  const int*   idx = (const int*)d_in[0];
  const float* emb = (const float*)d_in[1];
  const float* anw = (const float*)d_in[2];
  const float* qw  = (const float*)d_in[3];
  const float* qb  = (const float*)d_in[4];
  const float* kvw = (const float*)d_in[5];
  const float* kvb = (const float*)d_in[6];
  const float* ow  = (const float*)d_in[7];
  const float* ob  = (const float*)d_in[8];
  const float* fnw = (const float*)d_in[9];
  const float* rw  = (const float*)d_in[10];
  const float* gw  = (const float*)d_in[11];
  const float* uw  = (const float*)d_in[12];
  const float* dw  = (const float*)d_in[13];
  const float* lnf = (const float*)d_in[14];

  constexpr size_t MB = (size_t)1<<20;
  constexpr size_t KB = (size_t)1<<10;
  char* sc = (char*)d_out;
  Ptrs P;
  P.x     = (float*)sc;                                   // [0,4)
  P.hhi   = (unsigned short*)(sc + 4*MB);
  P.hlo   = (unsigned short*)(sc + 6*MB);
  P.qhi   = (unsigned short*)(sc + 8*MB);
  P.qlo   = (unsigned short*)(sc + 10*MB);
  P.khi   = (unsigned short*)(sc + 12*MB);
  P.klo   = (unsigned short*)(sc + 14*MB);
  P.vthi  = (unsigned short*)(sc + 16*MB);
  P.vtlo  = (unsigned short*)(sc + 18*MB);
  P.yhi   = (unsigned short*)(sc + 20*MB);
  P.ylo   = (unsigned short*)(sc + 22*MB);
  P.cmb   = (float*)(sc + 24*MB);                         // 16KB
  P.tl    = (int*)(sc + 24*MB + 64*KB);
  P.cwl   = (float*)(sc + 24*MB + 128*KB);
  P.cnt   = (int*)(sc + 24*MB + 192*KB);
  P.Hhi   = (unsigned short*)(sc + 25*MB);                // [25,41)
  P.Hlo   = (unsigned short*)(sc + 41*MB);                // [41,57)
  P.Wqkvh = (unsigned short*)(sc + 57*MB);                // [57,63)
  P.Wqkvl = (unsigned short*)(sc + 63*MB);                // [63,69)
  P.WOh   = (unsigned short*)(sc + 69*MB);                // [69,71)
  P.WOl   = (unsigned short*)(sc + 71*MB);                // [71,73)
  P.WGh   = (unsigned short*)(sc + 57*MB);                // reuse after attn done
  P.WGl   = (unsigned short*)(sc + 73*MB);
  P.WUh   = (unsigned short*)(sc + 89*MB);                // [89,105)
  P.WUl   = (unsigned short*)(sc + 105*MB);               // [105,121)
  P.WDh   = (unsigned short*)(sc + 57*MB);                // reuse after guf done
  P.WDl   = (unsigned short*)(sc + 73*MB);
  P.part  = (float*)(sc + 89*MB);                         // up to 32MB [89,121)
  unsigned short* xhat  = (unsigned short*)d_ws;          // 2 MiB, survives logits
  unsigned short* emb16 = (unsigned short*)((char*)d_ws + 2*MB); // 62.5 MiB (if ws allows)
  const bool big_ws = ws_size >= 68*MB;
  float* out = (float*)d_out;

  const int gbase = big_ws ? 16000 : 0;
  k_init<3><<<dim3(gbase + NT), dim3(256), 0, stream>>>(idx, emb, P.x, emb16, gbase,
      anw, P.hhi, P.hlo);

  run_layer<3>(P, 0, anw, qw, qb, kvw, kvb, ow, ob, fnw, rw, gw, uw, dw,
               anw + Dm, P.hhi, 1, 1.0f, stream);
  run_layer<1>(P, 1, anw, qw, qb, kvw, kvb, ow, ob, fnw, rw, gw, uw, dw,
               lnf, xhat, 0, 0.70710678f, stream);

  if (big_ws)
    k_lg16<<<dim3(500), dim3(512), 0, stream>>>(xhat, emb16, out);
  else
    k_lg<<<dim3(2000), dim3(256), 0, stream>>>(xhat, emb, out);
}